// Round 8
// baseline (1131.282 us; speedup 1.0000x reference)
//
#include <hip/hip_runtime.h>
#include <math.h>

// ---- problem constants ----
constexpr int BB   = 32;    // batch
constexpr int L    = 336;   // seq_len
constexpr int CIN  = 7;
constexpr int MARK = 4;
constexpr int D    = 512;   // d_model
constexpr int DFF  = 2048;
constexpr int NH   = 8;
constexpr int HD   = 64;    // dk = dv
constexpr int S    = 446;   // 336+84+21+5
constexpr int DBOT = 128;
constexpr int L1 = 84, L2 = 21, L3 = 5;
constexpr int LC = 110;     // 84+21+5
constexpr int NLAYER = 3;
constexpr int PRED_N = 672; // 96*7
constexpr int MP   = 14336; // BB*S=14272 padded to multiple of 128
constexpr int NMAX = 12;    // max sparse neighbors (real max 10)

using short8  = __attribute__((ext_vector_type(8))) short;
using float4v = __attribute__((ext_vector_type(4))) float;

__device__ inline short f2bf(float f) {
    union { float f; unsigned u; } v; v.f = f;
    unsigned r = v.u + 0x7fffu + ((v.u >> 16) & 1u);
    return (short)(r >> 16);
}
__device__ inline float bf2f(short h) {
    union { unsigned u; float f; } v; v.u = ((unsigned)(unsigned short)h) << 16;
    return v.f;
}

// async global->LDS, 16B per lane, wave-uniform LDS base + lane*16
__device__ inline void gload_lds16(const void* g, void* l) {
    __builtin_amdgcn_global_load_lds(
        (const __attribute__((address_space(1))) void*)g,
        (__attribute__((address_space(3))) void*)l, 16, 0, 0);
}

// ---------------------------------------------------------------------------
// bf16 MFMA GEMM: C[M,N] = A[M,K](bf16) @ Bt[N,K](bf16)^T
// 128x128 tile, BK=32, TRIPLE-buffered (48KB LDS), DEPTH-2 counted pipeline:
//   iter t: s_waitcnt vmcnt(4)   // own stage(t) done; stage(t+1) stays flying
//           s_barrier            // all waves' stage(t) done -> buf[t%3] valid
//           stage(t+2)           // writes buf[(t+2)%3]: != readers' t%3, (t+1)%3
//           ds_read buf[t%3] + 16 MFMA
//           s_barrier            // reads done before iter t+1 stages buf[(t+3)%3]
// stage(t) gets ~2 iterations of flight (covers L2/HBM latency) vs depth-1
// before. vmcnt is BEFORE the barrier so the barrier certifies cross-wave
// completion of stage(t) (each wave only tracks its own loads).
// XCD-aware bijective block swizzle (m204). EPI: 0 f32; 1 f32+bias; 2 bf16;
// 3 bf16+bias+gelu; 4 bf16+bias. grid.y*128 rows / grid.x*128 cols padded.
// ---------------------------------------------------------------------------
template<int EPI>
__launch_bounds__(256, 3)
__global__ void mfma_gemm(const short* __restrict__ A, const short* __restrict__ Bt,
                          const float* __restrict__ bias, void* __restrict__ Cout,
                          int Kd, int Nd) {
    __shared__ short As[3][128 * 32];
    __shared__ short Bs[3][128 * 32];
    int tid = threadIdx.x;
    // XCD-aware bijective swizzle (8 XCDs): contiguous wgid chunk per XCD
    int nwg  = gridDim.x * gridDim.y;
    int orig = blockIdx.y * gridDim.x + blockIdx.x;
    int qq = nwg >> 3, rr = nwg & 7;
    int xcd = orig & 7, idx = orig >> 3;
    int wgid = (xcd < rr ? xcd * (qq + 1) : rr * (qq + 1) + (xcd - rr) * qq) + idx;
    int m0 = (wgid / gridDim.x) * 128, n0 = (wgid % gridDim.x) * 128;

    int lane = tid & 63, wid = tid >> 6;
    int wm = wid >> 1, wn = wid & 1;
    int lr = lane & 15, lk = lane >> 4;

    auto stage = [&](int buf, int k0) {
#pragma unroll
        for (int r = 0; r < 2; ++r) {
            int cid = r * 256 + tid;
            int row = cid & 127, ks = cid >> 7;
            short* la = As[buf] + (size_t)(r * 256 + wid * 64) * 8;
            short* lb = Bs[buf] + (size_t)(r * 256 + wid * 64) * 8;
            gload_lds16(A + (size_t)(m0 + row) * Kd + k0 + ks * 8, la);
            gload_lds16(Bt + (size_t)(n0 + row) * Kd + k0 + ks * 8, lb);
        }
    };

    float4v acc[4][4];
#pragma unroll
    for (int i = 0; i < 4; ++i)
#pragma unroll
        for (int j = 0; j < 4; ++j) acc[i][j] = 0;

    const int nt = Kd >> 5;          // >= 4 for all our shapes
    stage(0, 0);
    stage(1, 32);
    int cur = 0;                     // t % 3
    for (int t = 0; t < nt; ++t) {
        if (t < nt - 1) {
            asm volatile("s_waitcnt vmcnt(4)" ::: "memory");  // own stage(t) done
        } else {
            asm volatile("s_waitcnt vmcnt(0)" ::: "memory");
        }
        __builtin_amdgcn_s_barrier();         // buf[cur] valid for all waves
        int wr = (cur == 0) ? 2 : cur - 1;    // (t+2) % 3
        if (t + 2 < nt) stage(wr, (t + 2) * 32);
        short8 af[4], bfv[4];
#pragma unroll
        for (int mi = 0; mi < 4; ++mi)
            af[mi] = *(const short8*)(As[cur] + ((size_t)lk * 128 + wm * 64 + mi * 16 + lr) * 8);
#pragma unroll
        for (int ni = 0; ni < 4; ++ni)
            bfv[ni] = *(const short8*)(Bs[cur] + ((size_t)lk * 128 + wn * 64 + ni * 16 + lr) * 8);
#pragma unroll
        for (int mi = 0; mi < 4; ++mi)
#pragma unroll
            for (int ni = 0; ni < 4; ++ni)
                acc[mi][ni] = __builtin_amdgcn_mfma_f32_16x16x32_bf16(
                    af[mi], bfv[ni], acc[mi][ni], 0, 0, 0);
        __builtin_amdgcn_s_barrier();         // reads of buf[cur] complete
        cur = (cur == 2) ? 0 : cur + 1;
    }

#pragma unroll
    for (int mi = 0; mi < 4; ++mi) {
        int gm = m0 + wm * 64 + mi * 16 + lk * 4;
#pragma unroll
        for (int ni = 0; ni < 4; ++ni) {
            int gn = n0 + wn * 64 + ni * 16 + lr;
            float bsv = (EPI == 1 || EPI == 3 || EPI == 4) ? bias[gn] : 0.0f;
#pragma unroll
            for (int e = 0; e < 4; ++e) {
                float v = acc[mi][ni][e] + bsv;
                if (EPI == 3) v = 0.5f * v * (1.0f + erff(v * 0.70710678118654752f));
                if (EPI <= 1) ((float*)Cout)[(size_t)(gm + e) * Nd + gn] = v;
                else          ((short*)Cout)[(size_t)(gm + e) * Nd + gn] = f2bf(v);
            }
        }
    }
}

// ---------------------------------------------------------------------------
// fp32 tiled GEMM (only the up-projection uses this). EPI: 1 = +bias
// ---------------------------------------------------------------------------
template<int EPI>
__launch_bounds__(256)
__global__ void gemm_kernel(const float* __restrict__ A, const float* __restrict__ Bm,
                            const float* __restrict__ bias, float* __restrict__ C,
                            int M, int N, int K) {
    __shared__ float As[16][65];
    __shared__ float Bs[16][65];
    int tid = threadIdx.x;
    int m0 = blockIdx.y * 64;
    int n0 = blockIdx.x * 64;
    int tx = tid & 15, ty = tid >> 4;
    float acc[4][4] = {};
    for (int k0 = 0; k0 < K; k0 += 16) {
#pragma unroll
        for (int r = 0; r < 4; ++r) {
            int id = tid + r * 256;
            int m = id >> 4, kk = id & 15;
            int gm = m0 + m, gk = k0 + kk;
            As[kk][m] = (gm < M && gk < K) ? A[(size_t)gm * K + gk] : 0.0f;
            int kb = id >> 6, n = id & 63;
            int gn = n0 + n, gkb = k0 + kb;
            Bs[kb][n] = (gkb < K && gn < N) ? Bm[(size_t)gkb * N + gn] : 0.0f;
        }
        __syncthreads();
#pragma unroll
        for (int kk = 0; kk < 16; ++kk) {
            float a[4], bv[4];
#pragma unroll
            for (int i = 0; i < 4; ++i) a[i] = As[kk][ty * 4 + i];
#pragma unroll
            for (int j = 0; j < 4; ++j) bv[j] = Bs[kk][tx * 4 + j];
#pragma unroll
            for (int i = 0; i < 4; ++i)
#pragma unroll
                for (int j = 0; j < 4; ++j)
                    acc[i][j] += a[i] * bv[j];
        }
        __syncthreads();
    }
#pragma unroll
    for (int i = 0; i < 4; ++i) {
        int gm = m0 + ty * 4 + i;
        if (gm >= M) continue;
#pragma unroll
        for (int j = 0; j < 4; ++j) {
            int gn = n0 + tx * 4 + j;
            if (gn >= N) continue;
            float v = acc[i][j];
            if (EPI >= 1) v += bias[gn];
            C[(size_t)gm * N + gn] = v;
        }
    }
}

// ---------------------------------------------------------------------------
// batched weight transpose+convert, 32x32 tiles, f32 W[Kd][Nd] -> bf16 Wt[Nd][Kd]
// ---------------------------------------------------------------------------
__device__ inline void wtrans_tile(const float* __restrict__ W, short* __restrict__ Wt,
                                   int Kd, int Nd, int n0, int k0, int tid) {
    __shared__ float tile[32][33];
    int tx = tid & 31, ty = tid >> 5; // ty 0..7
#pragma unroll
    for (int r = 0; r < 32; r += 8)
        tile[ty + r][tx] = W[(size_t)(k0 + ty + r) * Nd + n0 + tx];
    __syncthreads();
#pragma unroll
    for (int r = 0; r < 32; r += 8)
        Wt[(size_t)(n0 + ty + r) * Kd + k0 + tx] = f2bf(tile[tx][ty + r]);
}

// z = layer*4 + {0:q,1:k,2:v,3:o}; q/k/v pack into wqkvT [1536][512] per layer
__launch_bounds__(256)
__global__ void wtrans_qkvo(const float* __restrict__ wq, const float* __restrict__ wk,
                            const float* __restrict__ wv, const float* __restrict__ wo,
                            short* __restrict__ wqkvT, short* __restrict__ woT) {
    int z = blockIdx.z, l = z >> 2, part = z & 3;
    const float* src = (part == 0 ? wq : part == 1 ? wk : part == 2 ? wv : wo)
                       + (size_t)l * D * D;
    short* dst = (part < 3) ? wqkvT + (size_t)l * 3 * D * D + (size_t)part * D * D
                            : woT + (size_t)l * D * D;
    wtrans_tile(src, dst, D, D, blockIdx.x * 32, blockIdx.y * 32, threadIdx.x);
}

// z = layer*2 + {0:w1,1:w2}
__launch_bounds__(256)
__global__ void wtrans_ffn(const float* __restrict__ w1, const float* __restrict__ w2,
                           short* __restrict__ w1T, short* __restrict__ w2T) {
    int z = blockIdx.z, l = z >> 1, part = z & 1;
    int nt = part ? blockIdx.y : blockIdx.x;   // n-tiles: w1 64, w2 16
    int kt = part ? blockIdx.x : blockIdx.y;   // k-tiles: w1 16, w2 64
    if (part == 0)
        wtrans_tile(w1 + (size_t)l * D * DFF, w1T + (size_t)l * DFF * D,
                    D, DFF, nt * 32, kt * 32, threadIdx.x);
    else
        wtrans_tile(w2 + (size_t)l * DFF * D, w2T + (size_t)l * D * DFF,
                    DFF, D, nt * 32, kt * 32, threadIdx.x);
}

__launch_bounds__(256)
__global__ void wtrans_one(const float* __restrict__ W, short* __restrict__ Wt,
                           int Kd, int Nd) {
    wtrans_tile(W, Wt, Kd, Nd, blockIdx.x * 32, blockIdx.y * 32, threadIdx.x);
}

// ---------------------------------------------------------------------------
// Embedding: circular conv1d(k=3) + positional enc + mark @ time_w + time_b
// writes f32 and bf16 shadow
// ---------------------------------------------------------------------------
__launch_bounds__(256)
__global__ void embed_kernel(const float* __restrict__ x_enc, const float* __restrict__ x_mark,
                             const float* __restrict__ cw, const float* __restrict__ tw,
                             const float* __restrict__ tb, float* __restrict__ emb,
                             short* __restrict__ emb_bf) {
    size_t idx = (size_t)blockIdx.x * 256 + threadIdx.x;
    if (idx >= (size_t)BB * L * D) return;
    int d = idx % D;
    int t = (idx / D) % L;
    int b = idx / ((size_t)D * L);
    float acc = tb[d];
#pragma unroll
    for (int w = 0; w < 3; ++w) {
        int s = t + w - 1;
        if (s < 0) s = L - 1;
        if (s >= L) s = 0;
        const float* xr = x_enc + ((size_t)b * L + s) * CIN;
        const float* wr = cw + (size_t)d * (CIN * 3) + w;
#pragma unroll
        for (int i = 0; i < CIN; ++i) acc += xr[i] * wr[i * 3];
    }
    int e = d & ~1;
    float div = expf(-(float)e * (logf(10000.0f) / (float)D));
    float arg = (float)t * div;
    acc += (d & 1) ? cosf(arg) : sinf(arg);
    const float* mr = x_mark + ((size_t)b * L + t) * MARK;
#pragma unroll
    for (int m = 0; m < MARK; ++m) acc += mr[m] * tw[m * D + d];
    emb[idx] = acc;
    emb_bf[idx] = f2bf(acc);
}

// ---------------------------------------------------------------------------
// CSCM conv: kernel 4, stride 4; + bias, *bn_g + bn_b, ELU
// ---------------------------------------------------------------------------
__launch_bounds__(128)
__global__ void cscm_conv_kernel(const float* __restrict__ in, int inStride, int inOff,
                                 float* __restrict__ out, int outStride, int outOff, int Lout,
                                 const float* __restrict__ w, const float* __restrict__ cb,
                                 const float* __restrict__ bng, const float* __restrict__ bnb) {
    int bid = blockIdx.x;
    int to = bid % Lout, b = bid / Lout;
    __shared__ float insh[4 * DBOT];
    int tid = threadIdx.x;
#pragma unroll
    for (int r = 0; r < 4; ++r)
        insh[r * DBOT + tid] = in[((size_t)b * inStride + inOff + to * 4 + r) * DBOT + tid];
    __syncthreads();
    float acc = cb[tid];
    const float* wr = w + (size_t)tid * (DBOT * 4);
    for (int c = 0; c < DBOT; ++c) {
#pragma unroll
        for (int r = 0; r < 4; ++r)
            acc += insh[r * DBOT + c] * wr[c * 4 + r];
    }
    acc = acc * bng[tid] + bnb[tid];
    out[((size_t)b * outStride + outOff + to) * DBOT + tid] = acc > 0.0f ? acc : (expf(acc) - 1.0f);
}

// ---------------------------------------------------------------------------
// sparse neighbor lists from the pyramid mask rules
// ---------------------------------------------------------------------------
__device__ inline void layer_of(int i, int& l, int& p) {
    if (i < 336)      { l = 0; p = i; }
    else if (i < 420) { l = 1; p = i - 336; }
    else if (i < 441) { l = 2; p = i - 420; }
    else              { l = 3; p = i - 441; }
}

__launch_bounds__(64)
__global__ void nbr_kernel(int* __restrict__ nbr) {
    int i = blockIdx.x * 64 + threadIdx.x;
    if (i >= S) return;
    const int sizes[4]  = {336, 84, 21, 5};
    const int starts[4] = {0, 336, 420, 441};
    int li, pi;
    layer_of(i, li, pi);
    int lst[NMAX];
    int cnt = 0;
    for (int d = -2; d <= 2; ++d) {
        int q = pi + d;
        if (q >= 0 && q < sizes[li]) lst[cnt++] = starts[li] + q;
    }
    if (li > 0) {
        int lo = pi * 4;
        int hi = (pi == sizes[li] - 1) ? sizes[li - 1] : (pi + 1) * 4;
        for (int c = lo; c < hi; ++c) lst[cnt++] = starts[li - 1] + c;
    }
    if (li < 3) {
        int q = pi >> 2;
        if (q > sizes[li + 1] - 1) q = sizes[li + 1] - 1;
        lst[cnt++] = starts[li + 1] + q;
    }
    for (int j = 0; j < NMAX; ++j) nbr[i * NMAX + j] = (j < cnt) ? lst[j] : -1;
}

// ---------------------------------------------------------------------------
// sparse attention: one wave per (b,i), all 8 heads.
// lane covers channels lane*8..lane*8+7 (head h = lane>>3); short8 loads.
// QKV packed rows [1536]: Q at 0, K at 512, V at 1024.
// ---------------------------------------------------------------------------
__launch_bounds__(256)
__global__ void attn_sparse_kernel(const short* __restrict__ QKV, const int* __restrict__ nbr,
                                   short* __restrict__ Ob) {
    int wid  = blockIdx.x * 4 + (threadIdx.x >> 6);   // (b*S+i), exact: BB*S%4==0
    int lane = threadIdx.x & 63;
    int i = wid % S, b = wid / S;
    const short8 qv = *(const short8*)(QKV + (size_t)(b * S + i) * 1536 + lane * 8);
    float qf[8];
#pragma unroll
    for (int e = 0; e < 8; ++e) qf[e] = bf2f(qv[e]);
    int nb[NMAX];
    const int* nr = nbr + i * NMAX;
#pragma unroll
    for (int j = 0; j < NMAX; ++j) nb[j] = nr[j];
    float sc[NMAX];
#pragma unroll
    for (int j = 0; j < NMAX; ++j) {
        float s = -1e30f;
        if (nb[j] >= 0) {
            const short8 kv = *(const short8*)(QKV + (size_t)(b * S + nb[j]) * 1536 + 512 + lane * 8);
            s = 0.0f;
#pragma unroll
            for (int e = 0; e < 8; ++e) s += qf[e] * bf2f(kv[e]);
            s += __shfl_xor(s, 1); s += __shfl_xor(s, 2); s += __shfl_xor(s, 4);
            s *= 0.125f; // 1/sqrt(64)
        }
        sc[j] = s;
    }
    float mx = sc[0];
#pragma unroll
    for (int j = 1; j < NMAX; ++j) mx = fmaxf(mx, sc[j]);
    float sum = 0.0f;
    float accv[8] = {};
#pragma unroll
    for (int j = 0; j < NMAX; ++j) {
        float p = expf(sc[j] - mx);   // invalid -> exp(-huge) = 0
        sum += p;
        if (nb[j] >= 0) {
            const short8 vv = *(const short8*)(QKV + (size_t)(b * S + nb[j]) * 1536 + 1024 + lane * 8);
#pragma unroll
            for (int e = 0; e < 8; ++e) accv[e] += p * bf2f(vv[e]);
        }
    }
    float inv = 1.0f / sum;
    short8 ov;
#pragma unroll
    for (int e = 0; e < 8; ++e) ov[e] = f2bf(accv[e] * inv);
    *(short8*)(Ob + (size_t)(b * S + i) * D + lane * 8) = ov;
}

// ---------------------------------------------------------------------------
// concat(emb, coarse) + LayerNorm -> seq (f32) + seq_bf (bf16)
// ---------------------------------------------------------------------------
__launch_bounds__(256)
__global__ void concat_ln_kernel(const float* __restrict__ emb, const float* __restrict__ coarse,
                                 const float* __restrict__ g, const float* __restrict__ bta,
                                 float* __restrict__ seq, short* __restrict__ seq_bf) {
    int row = blockIdx.x;
    int b = row / S, s = row % S;
    const float* src = (s < L) ? emb + ((size_t)b * L + s) * D
                               : coarse + ((size_t)b * LC + (s - L)) * D;
    __shared__ float red[256];
    int tid = threadIdx.x;
    float x0 = src[tid], x1 = src[tid + 256];
    red[tid] = x0 + x1;
    __syncthreads();
    for (int t = 128; t > 0; t >>= 1) { if (tid < t) red[tid] += red[tid + t]; __syncthreads(); }
    float mu = red[0] * (1.0f / D);
    __syncthreads();
    float d0 = x0 - mu, d1 = x1 - mu;
    red[tid] = d0 * d0 + d1 * d1;
    __syncthreads();
    for (int t = 128; t > 0; t >>= 1) { if (tid < t) red[tid] += red[tid + t]; __syncthreads(); }
    float rstd = rsqrtf(red[0] * (1.0f / D) + 1e-5f);
    float v0 = d0 * rstd * g[tid]       + bta[tid];
    float v1 = d1 * rstd * g[tid + 256] + bta[tid + 256];
    float* dst = seq + (size_t)row * D;
    dst[tid] = v0; dst[tid + 256] = v1;
    short* dbf = seq_bf + (size_t)row * D;
    dbf[tid] = f2bf(v0); dbf[tid + 256] = f2bf(v1);
}

// ---------------------------------------------------------------------------
// seq = LN(seq + add) in place; add is bf16; writes bf16 shadow
// ---------------------------------------------------------------------------
__launch_bounds__(256)
__global__ void add_ln_kernel(float* __restrict__ seq, const short* __restrict__ add,
                              const float* __restrict__ g, const float* __restrict__ bta,
                              short* __restrict__ seq_bf) {
    int row = blockIdx.x;
    __shared__ float red[256];
    int tid = threadIdx.x;
    float* srow = seq + (size_t)row * D;
    const short* arow = add + (size_t)row * D;
    float x0 = srow[tid] + bf2f(arow[tid]);
    float x1 = srow[tid + 256] + bf2f(arow[tid + 256]);
    red[tid] = x0 + x1;
    __syncthreads();
    for (int t = 128; t > 0; t >>= 1) { if (tid < t) red[tid] += red[tid + t]; __syncthreads(); }
    float mu = red[0] * (1.0f / D);
    __syncthreads();
    float d0 = x0 - mu, d1 = x1 - mu;
    red[tid] = d0 * d0 + d1 * d1;
    __syncthreads();
    for (int t = 128; t > 0; t >>= 1) { if (tid < t) red[tid] += red[tid + t]; __syncthreads(); }
    float rstd = rsqrtf(red[0] * (1.0f / D) + 1e-5f);
    float v0 = d0 * rstd * g[tid]       + bta[tid];
    float v1 = d1 * rstd * g[tid + 256] + bta[tid + 256];
    srow[tid] = v0; srow[tid + 256] = v1;
    short* dbf = seq_bf + (size_t)row * D;
    dbf[tid] = f2bf(v0); dbf[tid + 256] = f2bf(v1);
}

// ---------------------------------------------------------------------------
// prediction head, split-K with fused gather:
// out[32][672] = enc[32][2048] @ w[2048][672], enc row b = seq rows {335,419,440,445}
// grid (84, 8): block = 8 cols x 256-row K-slice -> part[kslice][32][672]
// es padded to 257 to break the stride-256 8-way bank conflict.
// ---------------------------------------------------------------------------
__launch_bounds__(256)
__global__ void pred_kernel(const float* __restrict__ seq, const float* __restrict__ w,
                            float* __restrict__ part) {
    __shared__ float es[32][257];
    __shared__ float wsm[256][8];
    int tid = threadIdx.x;
    int n0 = blockIdx.x * 8;
    int ks = blockIdx.y;              // K slice: rows ks*256 .. ks*256+255
    int k0 = ks * 256;
    const int pos[4] = {335, 419, 440, 445};
    int seg = ks >> 1;                // which pyramid node (512 wide)
    int dbase = (ks & 1) * 256;
#pragma unroll 8
    for (int r = 0; r < 32; ++r)
        es[r][tid] = seq[((size_t)r * S + pos[seg]) * D + dbase + tid];
#pragma unroll
    for (int e = 0; e < 8; ++e)
        wsm[tid][e] = w[(size_t)(k0 + tid) * PRED_N + n0 + e];
    __syncthreads();
    int b = tid >> 3, nn = tid & 7;
    float acc = 0.0f;
#pragma unroll 8
    for (int kk = 0; kk < 256; ++kk)
        acc += es[b][kk] * wsm[kk][nn];
    part[(size_t)ks * (BB * PRED_N) + (size_t)b * PRED_N + n0 + nn] = acc;
}

__launch_bounds__(256)
__global__ void pred_reduce_kernel(const float* __restrict__ part, float* __restrict__ out) {
    int idx = blockIdx.x * 256 + threadIdx.x;
    if (idx >= BB * PRED_N) return;
    float s = 0.0f;
#pragma unroll
    for (int k = 0; k < 8; ++k) s += part[(size_t)k * (BB * PRED_N) + idx];
    out[idx] = s;
}

// ---------------------------------------------------------------------------
extern "C" void kernel_launch(void* const* d_in, const int* in_sizes, int n_in,
                              void* d_out, int out_size, void* d_ws, size_t ws_size,
                              hipStream_t stream) {
    const float* x_enc      = (const float*)d_in[0];
    const float* x_mark_enc = (const float*)d_in[1];
    const float* conv_embed_w = (const float*)d_in[4];
    const float* time_w  = (const float*)d_in[5];
    const float* time_b  = (const float*)d_in[6];
    const float* down_w  = (const float*)d_in[7];
    const float* down_b  = (const float*)d_in[8];
    const float* cscm_w  = (const float*)d_in[9];
    const float* cscm_b  = (const float*)d_in[10];
    const float* bn_g    = (const float*)d_in[11];
    const float* bn_b    = (const float*)d_in[12];
    const float* up_w    = (const float*)d_in[13];
    const float* up_b    = (const float*)d_in[14];
    const float* cln_g   = (const float*)d_in[15];
    const float* cln_b   = (const float*)d_in[16];
    const float* wq      = (const float*)d_in[17];
    const float* wk      = (const float*)d_in[18];
    const float* wv      = (const float*)d_in[19];
    const float* wo      = (const float*)d_in[20];
    const float* ln1_g   = (const float*)d_in[21];
    const float* ln1_b   = (const float*)d_in[22];
    const float* ffn_w1  = (const float*)d_in[23];
    const float* ffn_b1  = (const float*)d_in[24];
    const float* ffn_w2  = (const float*)d_in[25];
    const float* ffn_b2  = (const float*)d_in[26];
    const float* ln2_g   = (const float*)d_in[27];
    const float* ln2_b   = (const float*)d_in[28];
    const float* pred_w  = (const float*)d_in[29];
    float* out = (float*)d_out;

    // ---- workspace layout (bytes, 256-aligned) ----
    char* w8 = (char*)d_ws;
    size_t off = 0;
    auto alloc = [&](size_t bytes) {
        void* p = w8 + off;
        off = (off + bytes + 255) & ~(size_t)255;
        return p;
    };
    float* emb    = (float*)alloc((size_t)BB * L * D * 4);
    short* emb_bf = (short*)alloc((size_t)BB * L * D * 2);
    float* xd     = (float*)alloc((size_t)BB * L * DBOT * 4);
    float* cs     = (float*)alloc((size_t)BB * LC * DBOT * 4);
    float* coarse = (float*)alloc((size_t)BB * LC * D * 4);
    float* seq    = (float*)alloc((size_t)BB * S * D * 4);
    short* T1     = (short*)alloc((size_t)MP * D * 2);
    float* part   = (float*)alloc((size_t)8 * BB * PRED_N * 4);
    short* seq_bf = (short*)alloc((size_t)MP * D * 2);
    short* QKV    = (short*)alloc((size_t)MP * 3 * D * 2);  // + Ob contiguous =
    short* Ob     = (short*)alloc((size_t)MP * D * 2);      // hidden [MP][2048]
    short* hidden = QKV;
    short* wqkvT  = (short*)alloc((size_t)NLAYER * 3 * D * D * 2);
    short* woT    = (short*)alloc((size_t)NLAYER * D * D * 2);
    short* w1T    = (short*)alloc((size_t)NLAYER * DFF * D * 2);
    short* w2T    = (short*)alloc((size_t)NLAYER * D * DFF * 2);
    short* downT  = (short*)alloc((size_t)DBOT * D * 2);
    int*   nbr    = (int*)alloc((size_t)S * NMAX * 4);
    (void)ws_size; (void)in_sizes; (void)n_in; (void)out_size;

    const int rowsL = BB * L;   // 10752 = 84*128
    const int rowsS = BB * S;   // 14272
    const int rowsC = BB * LC;  // 3520
    dim3 blk(256);

    // 0. weight convert+transpose (3 batched launches)
    wtrans_qkvo<<<dim3(16, 16, 4 * NLAYER), blk, 0, stream>>>(wq, wk, wv, wo, wqkvT, woT);
    wtrans_ffn<<<dim3(64, 16, 2 * NLAYER), blk, 0, stream>>>(ffn_w1, ffn_w2, w1T, w2T);
    wtrans_one<<<dim3(DBOT / 32, D / 32), blk, 0, stream>>>(down_w, downT, D, DBOT);
    // 1. embedding + neighbor lists
    embed_kernel<<<dim3(((size_t)BB * L * D + 255) / 256), blk, 0, stream>>>(
        x_enc, x_mark_enc, conv_embed_w, time_w, time_b, emb, emb_bf);
    nbr_kernel<<<dim3((S + 63) / 64), dim3(64), 0, stream>>>(nbr);
    // 2. down projection (MFMA, M=10752 exact, N=128)
    mfma_gemm<1><<<dim3(1, rowsL / 128), blk, 0, stream>>>(
        emb_bf, downT, down_b, xd, D, DBOT);
    // 3. CSCM pyramid convs
    cscm_conv_kernel<<<dim3(BB * L1), dim3(DBOT), 0, stream>>>(
        xd, L, 0, cs, LC, 0, L1,
        cscm_w + 0 * DBOT * DBOT * 4, cscm_b + 0 * DBOT, bn_g + 0 * DBOT, bn_b + 0 * DBOT);
    cscm_conv_kernel<<<dim3(BB * L2), dim3(DBOT), 0, stream>>>(
        cs, LC, 0, cs, LC, L1, L2,
        cscm_w + 1 * DBOT * DBOT * 4, cscm_b + 1 * DBOT, bn_g + 1 * DBOT, bn_b + 1 * DBOT);
    cscm_conv_kernel<<<dim3(BB * L3), dim3(DBOT), 0, stream>>>(
        cs, LC, L1, cs, LC, L1 + L2, L3,
        cscm_w + 2 * DBOT * DBOT * 4, cscm_b + 2 * DBOT, bn_g + 2 * DBOT, bn_b + 2 * DBOT);
    // 4. up projection (fp32, small)
    gemm_kernel<1><<<dim3(D / 64, (rowsC + 63) / 64), blk, 0, stream>>>(
        cs, up_w, up_b, coarse, rowsC, D, DBOT);
    // 5. concat + LN
    concat_ln_kernel<<<dim3(rowsS), blk, 0, stream>>>(emb, coarse, cln_g, cln_b, seq, seq_bf);

    // 6. encoder layers
    const int gy = MP / 128; // 112
    for (int l = 0; l < NLAYER; ++l) {
        mfma_gemm<2><<<dim3(3 * D / 128, gy), blk, 0, stream>>>(
            seq_bf, wqkvT + (size_t)l * 3 * D * D, nullptr, QKV, D, 3 * D);
        attn_sparse_kernel<<<dim3(rowsS / 4), blk, 0, stream>>>(QKV, nbr, Ob);
        mfma_gemm<2><<<dim3(D / 128, gy), blk, 0, stream>>>(
            Ob, woT + (size_t)l * D * D, nullptr, T1, D, D);
        add_ln_kernel<<<dim3(rowsS), blk, 0, stream>>>(
            seq, T1, ln1_g + (size_t)l * D, ln1_b + (size_t)l * D, seq_bf);
        mfma_gemm<3><<<dim3(DFF / 128, gy), blk, 0, stream>>>(
            seq_bf, w1T + (size_t)l * DFF * D, ffn_b1 + (size_t)l * DFF, hidden, D, DFF);
        mfma_gemm<4><<<dim3(D / 128, gy), blk, 0, stream>>>(
            hidden, w2T + (size_t)l * D * DFF, ffn_b2 + (size_t)l * D, T1, DFF, D);
        add_ln_kernel<<<dim3(rowsS), blk, 0, stream>>>(
            seq, T1, ln2_g + (size_t)l * D, ln2_b + (size_t)l * D, seq_bf);
    }

    // 7. prediction head (split-K, gather fused) + reduce
    pred_kernel<<<dim3(PRED_N / 8, 8), blk, 0, stream>>>(seq, pred_w, part);
    pred_reduce_kernel<<<dim3((BB * PRED_N + 255) / 256), blk, 0, stream>>>(part, out);
}

// Round 9
// 949.807 us; speedup vs baseline: 1.1911x; 1.1911x over previous
//
#include <hip/hip_runtime.h>
#include <math.h>

// ---- problem constants ----
constexpr int BB   = 32;    // batch
constexpr int L    = 336;   // seq_len
constexpr int CIN  = 7;
constexpr int MARK = 4;
constexpr int D    = 512;   // d_model
constexpr int DFF  = 2048;
constexpr int NH   = 8;
constexpr int HD   = 64;    // dk = dv
constexpr int S    = 446;   // 336+84+21+5
constexpr int DBOT = 128;
constexpr int L1 = 84, L2 = 21, L3 = 5;
constexpr int LC = 110;     // 84+21+5
constexpr int NLAYER = 3;
constexpr int PRED_N = 672; // 96*7
constexpr int MP   = 14336; // BB*S=14272 padded to multiple of 256
constexpr int NMAX = 12;    // max sparse neighbors (real max 10)

using short8  = __attribute__((ext_vector_type(8))) short;
using float4v = __attribute__((ext_vector_type(4))) float;

__device__ inline short f2bf(float f) {
    union { float f; unsigned u; } v; v.f = f;
    unsigned r = v.u + 0x7fffu + ((v.u >> 16) & 1u);
    return (short)(r >> 16);
}
__device__ inline float bf2f(short h) {
    union { unsigned u; float f; } v; v.u = ((unsigned)(unsigned short)h) << 16;
    return v.f;
}

// async global->LDS, 16B per lane, wave-uniform LDS base + lane*16
__device__ inline void gload_lds16(const void* g, void* l) {
    __builtin_amdgcn_global_load_lds(
        (const __attribute__((address_space(1))) void*)g,
        (__attribute__((address_space(3))) void*)l, 16, 0, 0);
}

// Staging map (both GEMM kernels): LDS is row-major [rows][32k] bf16 per
// buffer. chunk cid covers (row = cid>>2, slot = cid&3); the lane fetches
// global kseg kg = slot ^ (row&3) ^ ((row>>2)&3) — a permutation WITHIN each
// row's 64B k-line, so 4 lanes/row still read one fully-used 64B line
// (coalesced: 16 lines/inst instead of 64 partial lines), while the XOR
// spreads the row-major bank pattern. Readers use the same XOR, which
// reduces to the per-lane constant slot = lk ^ (lr&3) ^ ((lr>>2)&3):
// 16-lane frag reads hit 16 distinct bank quads (conflict-free).

// ---------------------------------------------------------------------------
// 128x128 bf16 MFMA GEMM, BK=32, double-buffered (32KB), counted vmcnt(4)
// pipeline (round-7 skeleton, proven):
//   stage(t+1); s_waitcnt vmcnt(4); s_barrier; ds_read+16 MFMA; s_barrier
// EPI: 0 f32; 1 f32+bias; 2 bf16; 3 bf16+bias+gelu; 4 bf16+bias
// grid.y*128 rows / grid.x*128 cols must be readable/writable (M padded).
// ---------------------------------------------------------------------------
template<int EPI>
__launch_bounds__(256, 4)
__global__ void mfma_gemm(const short* __restrict__ A, const short* __restrict__ Bt,
                          const float* __restrict__ bias, void* __restrict__ Cout,
                          int Kd, int Nd) {
    __shared__ short As[2][128 * 32];
    __shared__ short Bs[2][128 * 32];
    int tid = threadIdx.x;
    // XCD-aware bijective swizzle (m204)
    int nwg  = gridDim.x * gridDim.y;
    int orig = blockIdx.y * gridDim.x + blockIdx.x;
    int qq = nwg >> 3, rr = nwg & 7;
    int xcd = orig & 7, idx = orig >> 3;
    int wgid = (xcd < rr ? xcd * (qq + 1) : rr * (qq + 1) + (xcd - rr) * qq) + idx;
    int m0 = (wgid / gridDim.x) * 128, n0 = (wgid % gridDim.x) * 128;

    int lane = tid & 63, wid = tid >> 6;
    int wm = wid >> 1, wn = wid & 1;
    int lr = lane & 15, lk = lane >> 4;
    int slot = (lk ^ (lr & 3) ^ ((lr >> 2) & 3)) & 3;   // per-lane constant

    auto stage = [&](int buf, int k0) {
#pragma unroll
        for (int r = 0; r < 2; ++r) {
            int cid = r * 256 + tid;                    // 512 chunks x 16B
            int row = cid >> 2;
            int kg  = ((cid & 3) ^ (row & 3) ^ ((row >> 2) & 3)) & 3;
            short* la = As[buf] + (size_t)(r * 256 + wid * 64) * 8;
            short* lb = Bs[buf] + (size_t)(r * 256 + wid * 64) * 8;
            gload_lds16(A + (size_t)(m0 + row) * Kd + k0 + kg * 8, la);
            gload_lds16(Bt + (size_t)(n0 + row) * Kd + k0 + kg * 8, lb);
        }
    };

    float4v acc[4][4];
#pragma unroll
    for (int i = 0; i < 4; ++i)
#pragma unroll
        for (int j = 0; j < 4; ++j) acc[i][j] = 0;

    const int nt = Kd >> 5;
    stage(0, 0);
    for (int t = 0; t < nt; ++t) {
        int cur = t & 1;
        if (t + 1 < nt) {
            stage(cur ^ 1, (t + 1) * 32);            // prefetch stays in flight
            asm volatile("s_waitcnt vmcnt(4)" ::: "memory");
        } else {
            asm volatile("s_waitcnt vmcnt(0)" ::: "memory");
        }
        __builtin_amdgcn_s_barrier();                // buf[cur] ready for all waves
        short8 af[4], bfv[4];
#pragma unroll
        for (int mi = 0; mi < 4; ++mi) {
            int row = wm * 64 + mi * 16 + lr;
            af[mi] = *(const short8*)(As[cur] + ((size_t)row * 4 + slot) * 8);
        }
#pragma unroll
        for (int ni = 0; ni < 4; ++ni) {
            int row = wn * 64 + ni * 16 + lr;
            bfv[ni] = *(const short8*)(Bs[cur] + ((size_t)row * 4 + slot) * 8);
        }
#pragma unroll
        for (int mi = 0; mi < 4; ++mi)
#pragma unroll
            for (int ni = 0; ni < 4; ++ni)
                acc[mi][ni] = __builtin_amdgcn_mfma_f32_16x16x32_bf16(
                    af[mi], bfv[ni], acc[mi][ni], 0, 0, 0);
        __builtin_amdgcn_s_barrier();                // all reads of buf[cur] done
    }

#pragma unroll
    for (int mi = 0; mi < 4; ++mi) {
        int gm = m0 + wm * 64 + mi * 16 + lk * 4;
#pragma unroll
        for (int ni = 0; ni < 4; ++ni) {
            int gn = n0 + wn * 64 + ni * 16 + lr;
            float bsv = (EPI == 1 || EPI == 3 || EPI == 4) ? bias[gn] : 0.0f;
#pragma unroll
            for (int e = 0; e < 4; ++e) {
                float v = acc[mi][ni][e] + bsv;
                if (EPI == 3) v = 0.5f * v * (1.0f + erff(v * 0.70710678118654752f));
                if (EPI <= 1) ((float*)Cout)[(size_t)(gm + e) * Nd + gn] = v;
                else          ((short*)Cout)[(size_t)(gm + e) * Nd + gn] = f2bf(v);
            }
        }
    }
}

// ---------------------------------------------------------------------------
// 256x256 bf16 MFMA GEMM (wide-N shapes: FFN1, QKV). 8 waves (2M x 4N),
// per-wave 128x64 output (8x4 frags), BK=32 double-buffered (64KB LDS),
// same counted-vmcnt skeleton & staging map as the 128x128 kernel.
// Halves staged bytes per FLOP vs 128x128. 1 block/CU (VGPR-capped).
// ---------------------------------------------------------------------------
template<int EPI>
__launch_bounds__(512, 2)
__global__ void mfma_gemm256(const short* __restrict__ A, const short* __restrict__ Bt,
                             const float* __restrict__ bias, void* __restrict__ Cout,
                             int Kd, int Nd) {
    __shared__ short As[2][256 * 32];
    __shared__ short Bs[2][256 * 32];
    int tid = threadIdx.x;
    int nwg  = gridDim.x * gridDim.y;
    int orig = blockIdx.y * gridDim.x + blockIdx.x;
    int qq = nwg >> 3, rr = nwg & 7;
    int xcd = orig & 7, idx = orig >> 3;
    int wgid = (xcd < rr ? xcd * (qq + 1) : rr * (qq + 1) + (xcd - rr) * qq) + idx;
    int m0 = (wgid / gridDim.x) * 256, n0 = (wgid % gridDim.x) * 256;

    int lane = tid & 63, wid = tid >> 6;
    int wm = wid >> 2, wn = wid & 3;
    int lr = lane & 15, lk = lane >> 4;
    int slot = (lk ^ (lr & 3) ^ ((lr >> 2) & 3)) & 3;

    auto stage = [&](int buf, int k0) {
#pragma unroll
        for (int r = 0; r < 2; ++r) {
            int cid = r * 512 + tid;                    // 1024 chunks x 16B
            int row = cid >> 2;
            int kg  = ((cid & 3) ^ (row & 3) ^ ((row >> 2) & 3)) & 3;
            short* la = As[buf] + (size_t)(r * 512 + wid * 64) * 8;
            short* lb = Bs[buf] + (size_t)(r * 512 + wid * 64) * 8;
            gload_lds16(A + (size_t)(m0 + row) * Kd + k0 + kg * 8, la);
            gload_lds16(Bt + (size_t)(n0 + row) * Kd + k0 + kg * 8, lb);
        }
    };

    float4v acc[8][4];
#pragma unroll
    for (int i = 0; i < 8; ++i)
#pragma unroll
        for (int j = 0; j < 4; ++j) acc[i][j] = 0;

    const int nt = Kd >> 5;
    stage(0, 0);
    for (int t = 0; t < nt; ++t) {
        int cur = t & 1;
        if (t + 1 < nt) {
            stage(cur ^ 1, (t + 1) * 32);
            asm volatile("s_waitcnt vmcnt(4)" ::: "memory");
        } else {
            asm volatile("s_waitcnt vmcnt(0)" ::: "memory");
        }
        __builtin_amdgcn_s_barrier();
        short8 af[8], bfv[4];
#pragma unroll
        for (int mi = 0; mi < 8; ++mi) {
            int row = wm * 128 + mi * 16 + lr;
            af[mi] = *(const short8*)(As[cur] + ((size_t)row * 4 + slot) * 8);
        }
#pragma unroll
        for (int ni = 0; ni < 4; ++ni) {
            int row = wn * 64 + ni * 16 + lr;
            bfv[ni] = *(const short8*)(Bs[cur] + ((size_t)row * 4 + slot) * 8);
        }
#pragma unroll
        for (int mi = 0; mi < 8; ++mi)
#pragma unroll
            for (int ni = 0; ni < 4; ++ni)
                acc[mi][ni] = __builtin_amdgcn_mfma_f32_16x16x32_bf16(
                    af[mi], bfv[ni], acc[mi][ni], 0, 0, 0);
        __builtin_amdgcn_s_barrier();
    }

#pragma unroll
    for (int mi = 0; mi < 8; ++mi) {
        int gm = m0 + wm * 128 + mi * 16 + lk * 4;
#pragma unroll
        for (int ni = 0; ni < 4; ++ni) {
            int gn = n0 + wn * 64 + ni * 16 + lr;
            float bsv = (EPI == 1 || EPI == 3 || EPI == 4) ? bias[gn] : 0.0f;
#pragma unroll
            for (int e = 0; e < 4; ++e) {
                float v = acc[mi][ni][e] + bsv;
                if (EPI == 3) v = 0.5f * v * (1.0f + erff(v * 0.70710678118654752f));
                if (EPI <= 1) ((float*)Cout)[(size_t)(gm + e) * Nd + gn] = v;
                else          ((short*)Cout)[(size_t)(gm + e) * Nd + gn] = f2bf(v);
            }
        }
    }
}

// ---------------------------------------------------------------------------
// fp32 tiled GEMM (only the up-projection uses this). EPI: 1 = +bias
// ---------------------------------------------------------------------------
template<int EPI>
__launch_bounds__(256)
__global__ void gemm_kernel(const float* __restrict__ A, const float* __restrict__ Bm,
                            const float* __restrict__ bias, float* __restrict__ C,
                            int M, int N, int K) {
    __shared__ float As[16][65];
    __shared__ float Bs[16][65];
    int tid = threadIdx.x;
    int m0 = blockIdx.y * 64;
    int n0 = blockIdx.x * 64;
    int tx = tid & 15, ty = tid >> 4;
    float acc[4][4] = {};
    for (int k0 = 0; k0 < K; k0 += 16) {
#pragma unroll
        for (int r = 0; r < 4; ++r) {
            int id = tid + r * 256;
            int m = id >> 4, kk = id & 15;
            int gm = m0 + m, gk = k0 + kk;
            As[kk][m] = (gm < M && gk < K) ? A[(size_t)gm * K + gk] : 0.0f;
            int kb = id >> 6, n = id & 63;
            int gn = n0 + n, gkb = k0 + kb;
            Bs[kb][n] = (gkb < K && gn < N) ? Bm[(size_t)gkb * N + gn] : 0.0f;
        }
        __syncthreads();
#pragma unroll
        for (int kk = 0; kk < 16; ++kk) {
            float a[4], bv[4];
#pragma unroll
            for (int i = 0; i < 4; ++i) a[i] = As[kk][ty * 4 + i];
#pragma unroll
            for (int j = 0; j < 4; ++j) bv[j] = Bs[kk][tx * 4 + j];
#pragma unroll
            for (int i = 0; i < 4; ++i)
#pragma unroll
                for (int j = 0; j < 4; ++j)
                    acc[i][j] += a[i] * bv[j];
        }
        __syncthreads();
    }
#pragma unroll
    for (int i = 0; i < 4; ++i) {
        int gm = m0 + ty * 4 + i;
        if (gm >= M) continue;
#pragma unroll
        for (int j = 0; j < 4; ++j) {
            int gn = n0 + tx * 4 + j;
            if (gn >= N) continue;
            float v = acc[i][j];
            if (EPI >= 1) v += bias[gn];
            C[(size_t)gm * N + gn] = v;
        }
    }
}

// ---------------------------------------------------------------------------
// batched weight transpose+convert, 32x32 tiles, f32 W[Kd][Nd] -> bf16 Wt[Nd][Kd]
// ---------------------------------------------------------------------------
__device__ inline void wtrans_tile(const float* __restrict__ W, short* __restrict__ Wt,
                                   int Kd, int Nd, int n0, int k0, int tid) {
    __shared__ float tile[32][33];
    int tx = tid & 31, ty = tid >> 5; // ty 0..7
#pragma unroll
    for (int r = 0; r < 32; r += 8)
        tile[ty + r][tx] = W[(size_t)(k0 + ty + r) * Nd + n0 + tx];
    __syncthreads();
#pragma unroll
    for (int r = 0; r < 32; r += 8)
        Wt[(size_t)(n0 + ty + r) * Kd + k0 + tx] = f2bf(tile[tx][ty + r]);
}

// z = layer*4 + {0:q,1:k,2:v,3:o}; q/k/v pack into wqkvT [1536][512] per layer
__launch_bounds__(256)
__global__ void wtrans_qkvo(const float* __restrict__ wq, const float* __restrict__ wk,
                            const float* __restrict__ wv, const float* __restrict__ wo,
                            short* __restrict__ wqkvT, short* __restrict__ woT) {
    int z = blockIdx.z, l = z >> 2, part = z & 3;
    const float* src = (part == 0 ? wq : part == 1 ? wk : part == 2 ? wv : wo)
                       + (size_t)l * D * D;
    short* dst = (part < 3) ? wqkvT + (size_t)l * 3 * D * D + (size_t)part * D * D
                            : woT + (size_t)l * D * D;
    wtrans_tile(src, dst, D, D, blockIdx.x * 32, blockIdx.y * 32, threadIdx.x);
}

// z = layer*2 + {0:w1,1:w2}
__launch_bounds__(256)
__global__ void wtrans_ffn(const float* __restrict__ w1, const float* __restrict__ w2,
                           short* __restrict__ w1T, short* __restrict__ w2T) {
    int z = blockIdx.z, l = z >> 1, part = z & 1;
    int nt = part ? blockIdx.y : blockIdx.x;   // n-tiles: w1 64, w2 16
    int kt = part ? blockIdx.x : blockIdx.y;   // k-tiles: w1 16, w2 64
    if (part == 0)
        wtrans_tile(w1 + (size_t)l * D * DFF, w1T + (size_t)l * DFF * D,
                    D, DFF, nt * 32, kt * 32, threadIdx.x);
    else
        wtrans_tile(w2 + (size_t)l * DFF * D, w2T + (size_t)l * D * DFF,
                    DFF, D, nt * 32, kt * 32, threadIdx.x);
}

__launch_bounds__(256)
__global__ void wtrans_one(const float* __restrict__ W, short* __restrict__ Wt,
                           int Kd, int Nd) {
    wtrans_tile(W, Wt, Kd, Nd, blockIdx.x * 32, blockIdx.y * 32, threadIdx.x);
}

// ---------------------------------------------------------------------------
// Embedding: circular conv1d(k=3) + positional enc + mark @ time_w + time_b
// writes f32 and bf16 shadow
// ---------------------------------------------------------------------------
__launch_bounds__(256)
__global__ void embed_kernel(const float* __restrict__ x_enc, const float* __restrict__ x_mark,
                             const float* __restrict__ cw, const float* __restrict__ tw,
                             const float* __restrict__ tb, float* __restrict__ emb,
                             short* __restrict__ emb_bf) {
    size_t idx = (size_t)blockIdx.x * 256 + threadIdx.x;
    if (idx >= (size_t)BB * L * D) return;
    int d = idx % D;
    int t = (idx / D) % L;
    int b = idx / ((size_t)D * L);
    float acc = tb[d];
#pragma unroll
    for (int w = 0; w < 3; ++w) {
        int s = t + w - 1;
        if (s < 0) s = L - 1;
        if (s >= L) s = 0;
        const float* xr = x_enc + ((size_t)b * L + s) * CIN;
        const float* wr = cw + (size_t)d * (CIN * 3) + w;
#pragma unroll
        for (int i = 0; i < CIN; ++i) acc += xr[i] * wr[i * 3];
    }
    int e = d & ~1;
    float div = expf(-(float)e * (logf(10000.0f) / (float)D));
    float arg = (float)t * div;
    acc += (d & 1) ? cosf(arg) : sinf(arg);
    const float* mr = x_mark + ((size_t)b * L + t) * MARK;
#pragma unroll
    for (int m = 0; m < MARK; ++m) acc += mr[m] * tw[m * D + d];
    emb[idx] = acc;
    emb_bf[idx] = f2bf(acc);
}

// ---------------------------------------------------------------------------
// CSCM conv: kernel 4, stride 4; + bias, *bn_g + bn_b, ELU
// ---------------------------------------------------------------------------
__launch_bounds__(128)
__global__ void cscm_conv_kernel(const float* __restrict__ in, int inStride, int inOff,
                                 float* __restrict__ out, int outStride, int outOff, int Lout,
                                 const float* __restrict__ w, const float* __restrict__ cb,
                                 const float* __restrict__ bng, const float* __restrict__ bnb) {
    int bid = blockIdx.x;
    int to = bid % Lout, b = bid / Lout;
    __shared__ float insh[4 * DBOT];
    int tid = threadIdx.x;
#pragma unroll
    for (int r = 0; r < 4; ++r)
        insh[r * DBOT + tid] = in[((size_t)b * inStride + inOff + to * 4 + r) * DBOT + tid];
    __syncthreads();
    float acc = cb[tid];
    const float* wr = w + (size_t)tid * (DBOT * 4);
    for (int c = 0; c < DBOT; ++c) {
#pragma unroll
        for (int r = 0; r < 4; ++r)
            acc += insh[r * DBOT + c] * wr[c * 4 + r];
    }
    acc = acc * bng[tid] + bnb[tid];
    out[((size_t)b * outStride + outOff + to) * DBOT + tid] = acc > 0.0f ? acc : (expf(acc) - 1.0f);
}

// ---------------------------------------------------------------------------
// sparse neighbor lists from the pyramid mask rules
// ---------------------------------------------------------------------------
__device__ inline void layer_of(int i, int& l, int& p) {
    if (i < 336)      { l = 0; p = i; }
    else if (i < 420) { l = 1; p = i - 336; }
    else if (i < 441) { l = 2; p = i - 420; }
    else              { l = 3; p = i - 441; }
}

__launch_bounds__(64)
__global__ void nbr_kernel(int* __restrict__ nbr) {
    int i = blockIdx.x * 64 + threadIdx.x;
    if (i >= S) return;
    const int sizes[4]  = {336, 84, 21, 5};
    const int starts[4] = {0, 336, 420, 441};
    int li, pi;
    layer_of(i, li, pi);
    int lst[NMAX];
    int cnt = 0;
    for (int d = -2; d <= 2; ++d) {
        int q = pi + d;
        if (q >= 0 && q < sizes[li]) lst[cnt++] = starts[li] + q;
    }
    if (li > 0) {
        int lo = pi * 4;
        int hi = (pi == sizes[li] - 1) ? sizes[li - 1] : (pi + 1) * 4;
        for (int c = lo; c < hi; ++c) lst[cnt++] = starts[li - 1] + c;
    }
    if (li < 3) {
        int q = pi >> 2;
        if (q > sizes[li + 1] - 1) q = sizes[li + 1] - 1;
        lst[cnt++] = starts[li + 1] + q;
    }
    for (int j = 0; j < NMAX; ++j) nbr[i * NMAX + j] = (j < cnt) ? lst[j] : -1;
}

// ---------------------------------------------------------------------------
// sparse attention: one wave per (b,i), all 8 heads.
// ---------------------------------------------------------------------------
__launch_bounds__(256)
__global__ void attn_sparse_kernel(const short* __restrict__ QKV, const int* __restrict__ nbr,
                                   short* __restrict__ Ob) {
    int wid  = blockIdx.x * 4 + (threadIdx.x >> 6);   // (b*S+i), exact: BB*S%4==0
    int lane = threadIdx.x & 63;
    int i = wid % S, b = wid / S;
    const short8 qv = *(const short8*)(QKV + (size_t)(b * S + i) * 1536 + lane * 8);
    float qf[8];
#pragma unroll
    for (int e = 0; e < 8; ++e) qf[e] = bf2f(qv[e]);
    int nb[NMAX];
    const int* nr = nbr + i * NMAX;
#pragma unroll
    for (int j = 0; j < NMAX; ++j) nb[j] = nr[j];
    float sc[NMAX];
#pragma unroll
    for (int j = 0; j < NMAX; ++j) {
        float s = -1e30f;
        if (nb[j] >= 0) {
            const short8 kv = *(const short8*)(QKV + (size_t)(b * S + nb[j]) * 1536 + 512 + lane * 8);
            s = 0.0f;
#pragma unroll
            for (int e = 0; e < 8; ++e) s += qf[e] * bf2f(kv[e]);
            s += __shfl_xor(s, 1); s += __shfl_xor(s, 2); s += __shfl_xor(s, 4);
            s *= 0.125f; // 1/sqrt(64)
        }
        sc[j] = s;
    }
    float mx = sc[0];
#pragma unroll
    for (int j = 1; j < NMAX; ++j) mx = fmaxf(mx, sc[j]);
    float sum = 0.0f;
    float accv[8] = {};
#pragma unroll
    for (int j = 0; j < NMAX; ++j) {
        float p = expf(sc[j] - mx);   // invalid -> exp(-huge) = 0
        sum += p;
        if (nb[j] >= 0) {
            const short8 vv = *(const short8*)(QKV + (size_t)(b * S + nb[j]) * 1536 + 1024 + lane * 8);
#pragma unroll
            for (int e = 0; e < 8; ++e) accv[e] += p * bf2f(vv[e]);
        }
    }
    float inv = 1.0f / sum;
    short8 ov;
#pragma unroll
    for (int e = 0; e < 8; ++e) ov[e] = f2bf(accv[e] * inv);
    *(short8*)(Ob + (size_t)(b * S + i) * D + lane * 8) = ov;
}

// ---------------------------------------------------------------------------
// concat(emb, coarse) + LayerNorm -> seq (f32) + seq_bf (bf16)
// ---------------------------------------------------------------------------
__launch_bounds__(256)
__global__ void concat_ln_kernel(const float* __restrict__ emb, const float* __restrict__ coarse,
                                 const float* __restrict__ g, const float* __restrict__ bta,
                                 float* __restrict__ seq, short* __restrict__ seq_bf) {
    int row = blockIdx.x;
    int b = row / S, s = row % S;
    const float* src = (s < L) ? emb + ((size_t)b * L + s) * D
                               : coarse + ((size_t)b * LC + (s - L)) * D;
    __shared__ float red[256];
    int tid = threadIdx.x;
    float x0 = src[tid], x1 = src[tid + 256];
    red[tid] = x0 + x1;
    __syncthreads();
    for (int t = 128; t > 0; t >>= 1) { if (tid < t) red[tid] += red[tid + t]; __syncthreads(); }
    float mu = red[0] * (1.0f / D);
    __syncthreads();
    float d0 = x0 - mu, d1 = x1 - mu;
    red[tid] = d0 * d0 + d1 * d1;
    __syncthreads();
    for (int t = 128; t > 0; t >>= 1) { if (tid < t) red[tid] += red[tid + t]; __syncthreads(); }
    float rstd = rsqrtf(red[0] * (1.0f / D) + 1e-5f);
    float v0 = d0 * rstd * g[tid]       + bta[tid];
    float v1 = d1 * rstd * g[tid + 256] + bta[tid + 256];
    float* dst = seq + (size_t)row * D;
    dst[tid] = v0; dst[tid + 256] = v1;
    short* dbf = seq_bf + (size_t)row * D;
    dbf[tid] = f2bf(v0); dbf[tid + 256] = f2bf(v1);
}

// ---------------------------------------------------------------------------
// seq = LN(seq + add) in place; add is bf16; writes bf16 shadow
// ---------------------------------------------------------------------------
__launch_bounds__(256)
__global__ void add_ln_kernel(float* __restrict__ seq, const short* __restrict__ add,
                              const float* __restrict__ g, const float* __restrict__ bta,
                              short* __restrict__ seq_bf) {
    int row = blockIdx.x;
    __shared__ float red[256];
    int tid = threadIdx.x;
    float* srow = seq + (size_t)row * D;
    const short* arow = add + (size_t)row * D;
    float x0 = srow[tid] + bf2f(arow[tid]);
    float x1 = srow[tid + 256] + bf2f(arow[tid + 256]);
    red[tid] = x0 + x1;
    __syncthreads();
    for (int t = 128; t > 0; t >>= 1) { if (tid < t) red[tid] += red[tid + t]; __syncthreads(); }
    float mu = red[0] * (1.0f / D);
    __syncthreads();
    float d0 = x0 - mu, d1 = x1 - mu;
    red[tid] = d0 * d0 + d1 * d1;
    __syncthreads();
    for (int t = 128; t > 0; t >>= 1) { if (tid < t) red[tid] += red[tid + t]; __syncthreads(); }
    float rstd = rsqrtf(red[0] * (1.0f / D) + 1e-5f);
    float v0 = d0 * rstd * g[tid]       + bta[tid];
    float v1 = d1 * rstd * g[tid + 256] + bta[tid + 256];
    srow[tid] = v0; srow[tid + 256] = v1;
    short* dbf = seq_bf + (size_t)row * D;
    dbf[tid] = f2bf(v0); dbf[tid + 256] = f2bf(v1);
}

// ---------------------------------------------------------------------------
// prediction head, split-K with fused gather (es padded to 257 for banks)
// ---------------------------------------------------------------------------
__launch_bounds__(256)
__global__ void pred_kernel(const float* __restrict__ seq, const float* __restrict__ w,
                            float* __restrict__ part) {
    __shared__ float es[32][257];
    __shared__ float wsm[256][8];
    int tid = threadIdx.x;
    int n0 = blockIdx.x * 8;
    int ks = blockIdx.y;              // K slice: rows ks*256 .. ks*256+255
    int k0 = ks * 256;
    const int pos[4] = {335, 419, 440, 445};
    int seg = ks >> 1;
    int dbase = (ks & 1) * 256;
#pragma unroll 8
    for (int r = 0; r < 32; ++r)
        es[r][tid] = seq[((size_t)r * S + pos[seg]) * D + dbase + tid];
#pragma unroll
    for (int e = 0; e < 8; ++e)
        wsm[tid][e] = w[(size_t)(k0 + tid) * PRED_N + n0 + e];
    __syncthreads();
    int b = tid >> 3, nn = tid & 7;
    float acc = 0.0f;
#pragma unroll 8
    for (int kk = 0; kk < 256; ++kk)
        acc += es[b][kk] * wsm[kk][nn];
    part[(size_t)ks * (BB * PRED_N) + (size_t)b * PRED_N + n0 + nn] = acc;
}

__launch_bounds__(256)
__global__ void pred_reduce_kernel(const float* __restrict__ part, float* __restrict__ out) {
    int idx = blockIdx.x * 256 + threadIdx.x;
    if (idx >= BB * PRED_N) return;
    float s = 0.0f;
#pragma unroll
    for (int k = 0; k < 8; ++k) s += part[(size_t)k * (BB * PRED_N) + idx];
    out[idx] = s;
}

// ---------------------------------------------------------------------------
extern "C" void kernel_launch(void* const* d_in, const int* in_sizes, int n_in,
                              void* d_out, int out_size, void* d_ws, size_t ws_size,
                              hipStream_t stream) {
    const float* x_enc      = (const float*)d_in[0];
    const float* x_mark_enc = (const float*)d_in[1];
    const float* conv_embed_w = (const float*)d_in[4];
    const float* time_w  = (const float*)d_in[5];
    const float* time_b  = (const float*)d_in[6];
    const float* down_w  = (const float*)d_in[7];
    const float* down_b  = (const float*)d_in[8];
    const float* cscm_w  = (const float*)d_in[9];
    const float* cscm_b  = (const float*)d_in[10];
    const float* bn_g    = (const float*)d_in[11];
    const float* bn_b    = (const float*)d_in[12];
    const float* up_w    = (const float*)d_in[13];
    const float* up_b    = (const float*)d_in[14];
    const float* cln_g   = (const float*)d_in[15];
    const float* cln_b   = (const float*)d_in[16];
    const float* wq      = (const float*)d_in[17];
    const float* wk      = (const float*)d_in[18];
    const float* wv      = (const float*)d_in[19];
    const float* wo      = (const float*)d_in[20];
    const float* ln1_g   = (const float*)d_in[21];
    const float* ln1_b   = (const float*)d_in[22];
    const float* ffn_w1  = (const float*)d_in[23];
    const float* ffn_b1  = (const float*)d_in[24];
    const float* ffn_w2  = (const float*)d_in[25];
    const float* ffn_b2  = (const float*)d_in[26];
    const float* ln2_g   = (const float*)d_in[27];
    const float* ln2_b   = (const float*)d_in[28];
    const float* pred_w  = (const float*)d_in[29];
    float* out = (float*)d_out;

    // ---- workspace layout (bytes, 256-aligned) ----
    char* w8 = (char*)d_ws;
    size_t off = 0;
    auto alloc = [&](size_t bytes) {
        void* p = w8 + off;
        off = (off + bytes + 255) & ~(size_t)255;
        return p;
    };
    float* emb    = (float*)alloc((size_t)BB * L * D * 4);
    short* emb_bf = (short*)alloc((size_t)BB * L * D * 2);
    float* xd     = (float*)alloc((size_t)BB * L * DBOT * 4);
    float* cs     = (float*)alloc((size_t)BB * LC * DBOT * 4);
    float* coarse = (float*)alloc((size_t)BB * LC * D * 4);
    float* seq    = (float*)alloc((size_t)BB * S * D * 4);
    short* T1     = (short*)alloc((size_t)MP * D * 2);
    float* part   = (float*)alloc((size_t)8 * BB * PRED_N * 4);
    short* seq_bf = (short*)alloc((size_t)MP * D * 2);
    short* QKV    = (short*)alloc((size_t)MP * 3 * D * 2);  // + Ob contiguous =
    short* Ob     = (short*)alloc((size_t)MP * D * 2);      // hidden [MP][2048]
    short* hidden = QKV;
    short* wqkvT  = (short*)alloc((size_t)NLAYER * 3 * D * D * 2);
    short* woT    = (short*)alloc((size_t)NLAYER * D * D * 2);
    short* w1T    = (short*)alloc((size_t)NLAYER * DFF * D * 2);
    short* w2T    = (short*)alloc((size_t)NLAYER * D * DFF * 2);
    short* downT  = (short*)alloc((size_t)DBOT * D * 2);
    int*   nbr    = (int*)alloc((size_t)S * NMAX * 4);
    (void)ws_size; (void)in_sizes; (void)n_in; (void)out_size;

    const int rowsL = BB * L;   // 10752 = 84*128
    const int rowsS = BB * S;   // 14272
    const int rowsC = BB * LC;  // 3520
    dim3 blk(256);

    // 0. weight convert+transpose (3 batched launches)
    wtrans_qkvo<<<dim3(16, 16, 4 * NLAYER), blk, 0, stream>>>(wq, wk, wv, wo, wqkvT, woT);
    wtrans_ffn<<<dim3(64, 16, 2 * NLAYER), blk, 0, stream>>>(ffn_w1, ffn_w2, w1T, w2T);
    wtrans_one<<<dim3(DBOT / 32, D / 32), blk, 0, stream>>>(down_w, downT, D, DBOT);
    // 1. embedding + neighbor lists
    embed_kernel<<<dim3(((size_t)BB * L * D + 255) / 256), blk, 0, stream>>>(
        x_enc, x_mark_enc, conv_embed_w, time_w, time_b, emb, emb_bf);
    nbr_kernel<<<dim3((S + 63) / 64), dim3(64), 0, stream>>>(nbr);
    // 2. down projection (MFMA, M=10752 exact, N=128)
    mfma_gemm<1><<<dim3(1, rowsL / 128), blk, 0, stream>>>(
        emb_bf, downT, down_b, xd, D, DBOT);
    // 3. CSCM pyramid convs
    cscm_conv_kernel<<<dim3(BB * L1), dim3(DBOT), 0, stream>>>(
        xd, L, 0, cs, LC, 0, L1,
        cscm_w + 0 * DBOT * DBOT * 4, cscm_b + 0 * DBOT, bn_g + 0 * DBOT, bn_b + 0 * DBOT);
    cscm_conv_kernel<<<dim3(BB * L2), dim3(DBOT), 0, stream>>>(
        cs, LC, 0, cs, LC, L1, L2,
        cscm_w + 1 * DBOT * DBOT * 4, cscm_b + 1 * DBOT, bn_g + 1 * DBOT, bn_b + 1 * DBOT);
    cscm_conv_kernel<<<dim3(BB * L3), dim3(DBOT), 0, stream>>>(
        cs, LC, L1, cs, LC, L1 + L2, L3,
        cscm_w + 2 * DBOT * DBOT * 4, cscm_b + 2 * DBOT, bn_g + 2 * DBOT, bn_b + 2 * DBOT);
    // 4. up projection (fp32, small)
    gemm_kernel<1><<<dim3(D / 64, (rowsC + 63) / 64), blk, 0, stream>>>(
        cs, up_w, up_b, coarse, rowsC, D, DBOT);
    // 5. concat + LN
    concat_ln_kernel<<<dim3(rowsS), blk, 0, stream>>>(emb, coarse, cln_g, cln_b, seq, seq_bf);

    // 6. encoder layers
    const int gy  = MP / 128;  // 112
    const int gy2 = MP / 256;  // 56
    for (int l = 0; l < NLAYER; ++l) {
        mfma_gemm256<2><<<dim3(3 * D / 256, gy2), dim3(512), 0, stream>>>(
            seq_bf, wqkvT + (size_t)l * 3 * D * D, nullptr, QKV, D, 3 * D);
        attn_sparse_kernel<<<dim3(rowsS / 4), blk, 0, stream>>>(QKV, nbr, Ob);
        mfma_gemm<2><<<dim3(D / 128, gy), blk, 0, stream>>>(
            Ob, woT + (size_t)l * D * D, nullptr, T1, D, D);
        add_ln_kernel<<<dim3(rowsS), blk, 0, stream>>>(
            seq, T1, ln1_g + (size_t)l * D, ln1_b + (size_t)l * D, seq_bf);
        mfma_gemm256<3><<<dim3(DFF / 256, gy2), dim3(512), 0, stream>>>(
            seq_bf, w1T + (size_t)l * DFF * D, ffn_b1 + (size_t)l * DFF, hidden, D, DFF);
        mfma_gemm<4><<<dim3(D / 128, gy), blk, 0, stream>>>(
            hidden, w2T + (size_t)l * D * DFF, ffn_b2 + (size_t)l * D, T1, DFF, D);
        add_ln_kernel<<<dim3(rowsS), blk, 0, stream>>>(
            seq, T1, ln2_g + (size_t)l * D, ln2_b + (size_t)l * D, seq_bf);
    }

    // 7. prediction head (split-K, gather fused) + reduce
    pred_kernel<<<dim3(PRED_N / 8, 8), blk, 0, stream>>>(seq, pred_w, part);
    pred_reduce_kernel<<<dim3((BB * PRED_N + 255) / 256), blk, 0, stream>>>(part, out);
}

// Round 10
// 862.967 us; speedup vs baseline: 1.3109x; 1.1006x over previous
//
#include <hip/hip_runtime.h>
#include <math.h>

// ---- problem constants ----
constexpr int BB   = 32;    // batch
constexpr int L    = 336;   // seq_len
constexpr int CIN  = 7;
constexpr int MARK = 4;
constexpr int D    = 512;   // d_model
constexpr int DFF  = 2048;
constexpr int NH   = 8;
constexpr int HD   = 64;    // dk = dv
constexpr int S    = 446;   // 336+84+21+5
constexpr int DBOT = 128;
constexpr int L1 = 84, L2 = 21, L3 = 5;
constexpr int LC = 110;     // 84+21+5
constexpr int NLAYER = 3;
constexpr int PRED_N = 672; // 96*7
constexpr int MP   = 14336; // BB*S=14272 padded to multiple of 256
constexpr int NMAX = 12;    // max sparse neighbors (real max 10)
constexpr int MCONV1 = BB * L1;          // 2688 = 21*128 (exact)
constexpr int MCONV2P = 768;             // BB*L2=672 padded to 6*128
constexpr int MCAT  = 3584;              // BB*LC=3520 padded to 28*128

using short8  = __attribute__((ext_vector_type(8))) short;
using float4v = __attribute__((ext_vector_type(4))) float;

__device__ inline short f2bf(float f) {
    union { float f; unsigned u; } v; v.f = f;
    unsigned r = v.u + 0x7fffu + ((v.u >> 16) & 1u);
    return (short)(r >> 16);
}
__device__ inline float bf2f(short h) {
    union { unsigned u; float f; } v; v.u = ((unsigned)(unsigned short)h) << 16;
    return v.f;
}

// async global->LDS, 16B per lane, wave-uniform LDS base + lane*16
__device__ inline void gload_lds16(const void* g, void* l) {
    __builtin_amdgcn_global_load_lds(
        (const __attribute__((address_space(1))) void*)g,
        (__attribute__((address_space(3))) void*)l, 16, 0, 0);
}

// Staging map (both GEMM kernels): LDS row-major [rows][32k] bf16 per buffer.
// chunk cid = (row = cid>>2, slot = cid&3); lane fetches global kseg
// kg = slot ^ (row&3) ^ ((row>>2)&3) — permutation WITHIN the row's 64B
// k-line (coalesced, 16 full lines/inst), spreads banks; readers use the
// per-lane constant slot = lk ^ (lr&3) ^ ((lr>>2)&3): conflict-free.

// ---------------------------------------------------------------------------
// 128x128 bf16 MFMA GEMM, BK=32, double-buffered, counted vmcnt(4) pipeline.
// EPI: 0 f32; 1 f32+bias; 2 bf16; 3 bf16+bias+gelu; 4 bf16+bias;
//      5 bf16, v = acc*bias[gn] + bias2[gn] then ELU  (fused conv BN+ELU)
// grid.y*128 rows / grid.x*128 cols must be readable/writable (M padded).
// ---------------------------------------------------------------------------
template<int EPI>
__launch_bounds__(256, 4)
__global__ void mfma_gemm(const short* __restrict__ A, const short* __restrict__ Bt,
                          const float* __restrict__ bias, const float* __restrict__ bias2,
                          void* __restrict__ Cout, int Kd, int Nd) {
    __shared__ short As[2][128 * 32];
    __shared__ short Bs[2][128 * 32];
    int tid = threadIdx.x;
    int nwg  = gridDim.x * gridDim.y;
    int orig = blockIdx.y * gridDim.x + blockIdx.x;
    int qq = nwg >> 3, rr = nwg & 7;
    int xcd = orig & 7, idx = orig >> 3;
    int wgid = (xcd < rr ? xcd * (qq + 1) : rr * (qq + 1) + (xcd - rr) * qq) + idx;
    int m0 = (wgid / gridDim.x) * 128, n0 = (wgid % gridDim.x) * 128;

    int lane = tid & 63, wid = tid >> 6;
    int wm = wid >> 1, wn = wid & 1;
    int lr = lane & 15, lk = lane >> 4;
    int slot = (lk ^ (lr & 3) ^ ((lr >> 2) & 3)) & 3;

    auto stage = [&](int buf, int k0) {
#pragma unroll
        for (int r = 0; r < 2; ++r) {
            int cid = r * 256 + tid;
            int row = cid >> 2;
            int kg  = ((cid & 3) ^ (row & 3) ^ ((row >> 2) & 3)) & 3;
            short* la = As[buf] + (size_t)(r * 256 + wid * 64) * 8;
            short* lb = Bs[buf] + (size_t)(r * 256 + wid * 64) * 8;
            gload_lds16(A + (size_t)(m0 + row) * Kd + k0 + kg * 8, la);
            gload_lds16(Bt + (size_t)(n0 + row) * Kd + k0 + kg * 8, lb);
        }
    };

    float4v acc[4][4];
#pragma unroll
    for (int i = 0; i < 4; ++i)
#pragma unroll
        for (int j = 0; j < 4; ++j) acc[i][j] = 0;

    const int nt = Kd >> 5;
    stage(0, 0);
    for (int t = 0; t < nt; ++t) {
        int cur = t & 1;
        if (t + 1 < nt) {
            stage(cur ^ 1, (t + 1) * 32);
            asm volatile("s_waitcnt vmcnt(4)" ::: "memory");
        } else {
            asm volatile("s_waitcnt vmcnt(0)" ::: "memory");
        }
        __builtin_amdgcn_s_barrier();
        short8 af[4], bfv[4];
#pragma unroll
        for (int mi = 0; mi < 4; ++mi) {
            int row = wm * 64 + mi * 16 + lr;
            af[mi] = *(const short8*)(As[cur] + ((size_t)row * 4 + slot) * 8);
        }
#pragma unroll
        for (int ni = 0; ni < 4; ++ni) {
            int row = wn * 64 + ni * 16 + lr;
            bfv[ni] = *(const short8*)(Bs[cur] + ((size_t)row * 4 + slot) * 8);
        }
#pragma unroll
        for (int mi = 0; mi < 4; ++mi)
#pragma unroll
            for (int ni = 0; ni < 4; ++ni)
                acc[mi][ni] = __builtin_amdgcn_mfma_f32_16x16x32_bf16(
                    af[mi], bfv[ni], acc[mi][ni], 0, 0, 0);
        __builtin_amdgcn_s_barrier();
    }

#pragma unroll
    for (int mi = 0; mi < 4; ++mi) {
        int gm = m0 + wm * 64 + mi * 16 + lk * 4;
#pragma unroll
        for (int ni = 0; ni < 4; ++ni) {
            int gn = n0 + wn * 64 + ni * 16 + lr;
            float bsv = (EPI == 1 || EPI == 3 || EPI == 4) ? bias[gn] : 0.0f;
            float sc = (EPI == 5) ? bias[gn]  : 0.0f;
            float sh = (EPI == 5) ? bias2[gn] : 0.0f;
#pragma unroll
            for (int e = 0; e < 4; ++e) {
                float v = acc[mi][ni][e] + bsv;
                if (EPI == 3) v = 0.5f * v * (1.0f + erff(v * 0.70710678118654752f));
                if (EPI == 5) { v = v * sc + sh; v = v > 0.0f ? v : (expf(v) - 1.0f); }
                if (EPI <= 1) ((float*)Cout)[(size_t)(gm + e) * Nd + gn] = v;
                else          ((short*)Cout)[(size_t)(gm + e) * Nd + gn] = f2bf(v);
            }
        }
    }
}

// ---------------------------------------------------------------------------
// 256x256 bf16 MFMA GEMM (wide-N shapes: FFN1, QKV). 8 waves (2M x 4N),
// BK=32 double-buffered (64KB LDS), same counted-vmcnt skeleton & staging.
// ---------------------------------------------------------------------------
template<int EPI>
__launch_bounds__(512, 2)
__global__ void mfma_gemm256(const short* __restrict__ A, const short* __restrict__ Bt,
                             const float* __restrict__ bias, void* __restrict__ Cout,
                             int Kd, int Nd) {
    __shared__ short As[2][256 * 32];
    __shared__ short Bs[2][256 * 32];
    int tid = threadIdx.x;
    int nwg  = gridDim.x * gridDim.y;
    int orig = blockIdx.y * gridDim.x + blockIdx.x;
    int qq = nwg >> 3, rr = nwg & 7;
    int xcd = orig & 7, idx = orig >> 3;
    int wgid = (xcd < rr ? xcd * (qq + 1) : rr * (qq + 1) + (xcd - rr) * qq) + idx;
    int m0 = (wgid / gridDim.x) * 256, n0 = (wgid % gridDim.x) * 256;

    int lane = tid & 63, wid = tid >> 6;
    int wm = wid >> 2, wn = wid & 3;
    int lr = lane & 15, lk = lane >> 4;
    int slot = (lk ^ (lr & 3) ^ ((lr >> 2) & 3)) & 3;

    auto stage = [&](int buf, int k0) {
#pragma unroll
        for (int r = 0; r < 2; ++r) {
            int cid = r * 512 + tid;
            int row = cid >> 2;
            int kg  = ((cid & 3) ^ (row & 3) ^ ((row >> 2) & 3)) & 3;
            short* la = As[buf] + (size_t)(r * 512 + wid * 64) * 8;
            short* lb = Bs[buf] + (size_t)(r * 512 + wid * 64) * 8;
            gload_lds16(A + (size_t)(m0 + row) * Kd + k0 + kg * 8, la);
            gload_lds16(Bt + (size_t)(n0 + row) * Kd + k0 + kg * 8, lb);
        }
    };

    float4v acc[8][4];
#pragma unroll
    for (int i = 0; i < 8; ++i)
#pragma unroll
        for (int j = 0; j < 4; ++j) acc[i][j] = 0;

    const int nt = Kd >> 5;
    stage(0, 0);
    for (int t = 0; t < nt; ++t) {
        int cur = t & 1;
        if (t + 1 < nt) {
            stage(cur ^ 1, (t + 1) * 32);
            asm volatile("s_waitcnt vmcnt(4)" ::: "memory");
        } else {
            asm volatile("s_waitcnt vmcnt(0)" ::: "memory");
        }
        __builtin_amdgcn_s_barrier();
        short8 af[8], bfv[4];
#pragma unroll
        for (int mi = 0; mi < 8; ++mi) {
            int row = wm * 128 + mi * 16 + lr;
            af[mi] = *(const short8*)(As[cur] + ((size_t)row * 4 + slot) * 8);
        }
#pragma unroll
        for (int ni = 0; ni < 4; ++ni) {
            int row = wn * 64 + ni * 16 + lr;
            bfv[ni] = *(const short8*)(Bs[cur] + ((size_t)row * 4 + slot) * 8);
        }
#pragma unroll
        for (int mi = 0; mi < 8; ++mi)
#pragma unroll
            for (int ni = 0; ni < 4; ++ni)
                acc[mi][ni] = __builtin_amdgcn_mfma_f32_16x16x32_bf16(
                    af[mi], bfv[ni], acc[mi][ni], 0, 0, 0);
        __builtin_amdgcn_s_barrier();
    }

#pragma unroll
    for (int mi = 0; mi < 8; ++mi) {
        int gm = m0 + wm * 128 + mi * 16 + lk * 4;
#pragma unroll
        for (int ni = 0; ni < 4; ++ni) {
            int gn = n0 + wn * 64 + ni * 16 + lr;
            float bsv = (EPI == 1 || EPI == 3 || EPI == 4) ? bias[gn] : 0.0f;
#pragma unroll
            for (int e = 0; e < 4; ++e) {
                float v = acc[mi][ni][e] + bsv;
                if (EPI == 3) v = 0.5f * v * (1.0f + erff(v * 0.70710678118654752f));
                if (EPI <= 1) ((float*)Cout)[(size_t)(gm + e) * Nd + gn] = v;
                else          ((short*)Cout)[(size_t)(gm + e) * Nd + gn] = f2bf(v);
            }
        }
    }
}

// ---------------------------------------------------------------------------
// batched weight transpose+convert, 32x32 tiles, f32 W[Kd][Nd] -> bf16 Wt[Nd][Kd]
// ---------------------------------------------------------------------------
__device__ inline void wtrans_tile(const float* __restrict__ W, short* __restrict__ Wt,
                                   int Kd, int Nd, int n0, int k0, int tid) {
    __shared__ float tile[32][33];
    int tx = tid & 31, ty = tid >> 5; // ty 0..7
#pragma unroll
    for (int r = 0; r < 32; r += 8)
        tile[ty + r][tx] = W[(size_t)(k0 + ty + r) * Nd + n0 + tx];
    __syncthreads();
#pragma unroll
    for (int r = 0; r < 32; r += 8)
        Wt[(size_t)(n0 + ty + r) * Kd + k0 + tx] = f2bf(tile[tx][ty + r]);
}

// z = layer*4 + {0:q,1:k,2:v,3:o}; q/k/v pack into wqkvT [1536][512] per layer
__launch_bounds__(256)
__global__ void wtrans_qkvo(const float* __restrict__ wq, const float* __restrict__ wk,
                            const float* __restrict__ wv, const float* __restrict__ wo,
                            short* __restrict__ wqkvT, short* __restrict__ woT) {
    int z = blockIdx.z, l = z >> 2, part = z & 3;
    const float* src = (part == 0 ? wq : part == 1 ? wk : part == 2 ? wv : wo)
                       + (size_t)l * D * D;
    short* dst = (part < 3) ? wqkvT + (size_t)l * 3 * D * D + (size_t)part * D * D
                            : woT + (size_t)l * D * D;
    wtrans_tile(src, dst, D, D, blockIdx.x * 32, blockIdx.y * 32, threadIdx.x);
}

// z = layer*2 + {0:w1,1:w2}
__launch_bounds__(256)
__global__ void wtrans_ffn(const float* __restrict__ w1, const float* __restrict__ w2,
                           short* __restrict__ w1T, short* __restrict__ w2T) {
    int z = blockIdx.z, l = z >> 1, part = z & 1;
    int nt = part ? blockIdx.y : blockIdx.x;   // n-tiles: w1 64, w2 16
    int kt = part ? blockIdx.x : blockIdx.y;   // k-tiles: w1 16, w2 64
    if (part == 0)
        wtrans_tile(w1 + (size_t)l * D * DFF, w1T + (size_t)l * DFF * D,
                    D, DFF, nt * 32, kt * 32, threadIdx.x);
    else
        wtrans_tile(w2 + (size_t)l * DFF * D, w2T + (size_t)l * D * DFF,
                    DFF, D, nt * 32, kt * 32, threadIdx.x);
}

__launch_bounds__(256)
__global__ void wtrans_one(const float* __restrict__ W, short* __restrict__ Wt,
                           int Kd, int Nd) {
    wtrans_tile(W, Wt, Kd, Nd, blockIdx.x * 32, blockIdx.y * 32, threadIdx.x);
}

// ---------------------------------------------------------------------------
// CSCM prep: levels 0,1 weights -> GEMM layout cscmT[l][oc][r*128+c] (bf16);
// per-channel fused BN: sc = bn_g, sh = cb*bn_g + bn_b (all 3 levels)
// ---------------------------------------------------------------------------
__launch_bounds__(256)
__global__ void cscm_prep(const float* __restrict__ cw, const float* __restrict__ cb,
                          const float* __restrict__ bg, const float* __restrict__ bb,
                          short* __restrict__ cscmT, float* __restrict__ sc,
                          float* __restrict__ sh) {
    int idx = blockIdx.x * 256 + threadIdx.x;
    if (idx < 2 * DBOT * 512) {
        int l = idx >> 16;           // 128*512 = 65536
        int rem = idx & 65535;
        int oc = rem >> 9, j = rem & 511;
        int r = j >> 7, c = j & 127;
        cscmT[idx] = f2bf(cw[(((size_t)l * DBOT + oc) * DBOT + c) * 4 + r]);
    }
    if (idx < 3 * DBOT) {
        sc[idx] = bg[idx];
        sh[idx] = cb[idx] * bg[idx] + bb[idx];
    }
}

// ---------------------------------------------------------------------------
// Embedding: circular conv1d(k=3) + positional enc + mark @ time_w + time_b
// ---------------------------------------------------------------------------
__launch_bounds__(256)
__global__ void embed_kernel(const float* __restrict__ x_enc, const float* __restrict__ x_mark,
                             const float* __restrict__ cw, const float* __restrict__ tw,
                             const float* __restrict__ tb, float* __restrict__ emb,
                             short* __restrict__ emb_bf) {
    size_t idx = (size_t)blockIdx.x * 256 + threadIdx.x;
    if (idx >= (size_t)BB * L * D) return;
    int d = idx % D;
    int t = (idx / D) % L;
    int b = idx / ((size_t)D * L);
    float acc = tb[d];
#pragma unroll
    for (int w = 0; w < 3; ++w) {
        int s = t + w - 1;
        if (s < 0) s = L - 1;
        if (s >= L) s = 0;
        const float* xr = x_enc + ((size_t)b * L + s) * CIN;
        const float* wr = cw + (size_t)d * (CIN * 3) + w;
#pragma unroll
        for (int i = 0; i < CIN; ++i) acc += xr[i] * wr[i * 3];
    }
    int e = d & ~1;
    float div = expf(-(float)e * (logf(10000.0f) / (float)D));
    float arg = (float)t * div;
    acc += (d & 1) ? cosf(arg) : sinf(arg);
    const float* mr = x_mark + ((size_t)b * L + t) * MARK;
#pragma unroll
    for (int m = 0; m < MARK; ++m) acc += mr[m] * tw[m * D + d];
    emb[idx] = acc;
    emb_bf[idx] = f2bf(acc);
}

// ---------------------------------------------------------------------------
// CSCM conv level 3 only (tiny): bf16 in/out, f32 weights
// ---------------------------------------------------------------------------
__launch_bounds__(128)
__global__ void cscm_conv_bf16(const short* __restrict__ in, int inRowsPerB,
                               short* __restrict__ outp, const float* __restrict__ w,
                               const float* __restrict__ cb, const float* __restrict__ bng,
                               const float* __restrict__ bnb, int Lout) {
    int bid = blockIdx.x;
    int to = bid % Lout, b = bid / Lout;
    __shared__ float insh[4 * DBOT];
    int tid = threadIdx.x;
#pragma unroll
    for (int r = 0; r < 4; ++r)
        insh[r * DBOT + tid] = bf2f(in[((size_t)(b * inRowsPerB + to * 4 + r)) * DBOT + tid]);
    __syncthreads();
    float acc = cb[tid];
    const float* wr = w + (size_t)tid * (DBOT * 4);
    for (int c = 0; c < DBOT; ++c) {
#pragma unroll
        for (int r = 0; r < 4; ++r)
            acc += insh[r * DBOT + c] * wr[c * 4 + r];
    }
    acc = acc * bng[tid] + bnb[tid];
    outp[((size_t)(b * Lout + to)) * DBOT + tid] = f2bf(acc > 0.0f ? acc : (expf(acc) - 1.0f));
}

// ---------------------------------------------------------------------------
// concat pyramid outputs (bf16) -> csc [MCAT][128] for the up-projection GEMM
// ---------------------------------------------------------------------------
__launch_bounds__(256)
__global__ void concat_cs_kernel(const short* __restrict__ cs1, const short* __restrict__ cs2,
                                 const short* __restrict__ cs3, short* __restrict__ csc) {
    int idx = blockIdx.x * 256 + threadIdx.x;
    if (idx >= MCAT * DBOT) return;
    int m = idx >> 7, c = idx & 127;
    short v = 0;
    if (m < BB * LC) {
        int b = m / LC, t = m % LC;
        if (t < L1)           v = cs1[(size_t)(b * L1 + t) * DBOT + c];
        else if (t < L1 + L2) v = cs2[(size_t)(b * L2 + (t - L1)) * DBOT + c];
        else                  v = cs3[(size_t)(b * L3 + (t - L1 - L2)) * DBOT + c];
    }
    csc[idx] = v;
}

// ---------------------------------------------------------------------------
// sparse neighbor lists from the pyramid mask rules
// ---------------------------------------------------------------------------
__device__ inline void layer_of(int i, int& l, int& p) {
    if (i < 336)      { l = 0; p = i; }
    else if (i < 420) { l = 1; p = i - 336; }
    else if (i < 441) { l = 2; p = i - 420; }
    else              { l = 3; p = i - 441; }
}

__launch_bounds__(64)
__global__ void nbr_kernel(int* __restrict__ nbr) {
    int i = blockIdx.x * 64 + threadIdx.x;
    if (i >= S) return;
    const int sizes[4]  = {336, 84, 21, 5};
    const int starts[4] = {0, 336, 420, 441};
    int li, pi;
    layer_of(i, li, pi);
    int lst[NMAX];
    int cnt = 0;
    for (int d = -2; d <= 2; ++d) {
        int q = pi + d;
        if (q >= 0 && q < sizes[li]) lst[cnt++] = starts[li] + q;
    }
    if (li > 0) {
        int lo = pi * 4;
        int hi = (pi == sizes[li] - 1) ? sizes[li - 1] : (pi + 1) * 4;
        for (int c = lo; c < hi; ++c) lst[cnt++] = starts[li - 1] + c;
    }
    if (li < 3) {
        int q = pi >> 2;
        if (q > sizes[li + 1] - 1) q = sizes[li + 1] - 1;
        lst[cnt++] = starts[li + 1] + q;
    }
    for (int j = 0; j < NMAX; ++j) nbr[i * NMAX + j] = (j < cnt) ? lst[j] : -1;
}

// ---------------------------------------------------------------------------
// sparse attention: one wave per (b,i), all 8 heads.
// ---------------------------------------------------------------------------
__launch_bounds__(256)
__global__ void attn_sparse_kernel(const short* __restrict__ QKV, const int* __restrict__ nbr,
                                   short* __restrict__ Ob) {
    int wid  = blockIdx.x * 4 + (threadIdx.x >> 6);   // (b*S+i), exact: BB*S%4==0
    int lane = threadIdx.x & 63;
    int i = wid % S, b = wid / S;
    const short8 qv = *(const short8*)(QKV + (size_t)(b * S + i) * 1536 + lane * 8);
    float qf[8];
#pragma unroll
    for (int e = 0; e < 8; ++e) qf[e] = bf2f(qv[e]);
    int nb[NMAX];
    const int* nr = nbr + i * NMAX;
#pragma unroll
    for (int j = 0; j < NMAX; ++j) nb[j] = nr[j];
    float sc[NMAX];
#pragma unroll
    for (int j = 0; j < NMAX; ++j) {
        float s = -1e30f;
        if (nb[j] >= 0) {
            const short8 kv = *(const short8*)(QKV + (size_t)(b * S + nb[j]) * 1536 + 512 + lane * 8);
            s = 0.0f;
#pragma unroll
            for (int e = 0; e < 8; ++e) s += qf[e] * bf2f(kv[e]);
            s += __shfl_xor(s, 1); s += __shfl_xor(s, 2); s += __shfl_xor(s, 4);
            s *= 0.125f; // 1/sqrt(64)
        }
        sc[j] = s;
    }
    float mx = sc[0];
#pragma unroll
    for (int j = 1; j < NMAX; ++j) mx = fmaxf(mx, sc[j]);
    float sum = 0.0f;
    float accv[8] = {};
#pragma unroll
    for (int j = 0; j < NMAX; ++j) {
        float p = expf(sc[j] - mx);   // invalid -> exp(-huge) = 0
        sum += p;
        if (nb[j] >= 0) {
            const short8 vv = *(const short8*)(QKV + (size_t)(b * S + nb[j]) * 1536 + 1024 + lane * 8);
#pragma unroll
            for (int e = 0; e < 8; ++e) accv[e] += p * bf2f(vv[e]);
        }
    }
    float inv = 1.0f / sum;
    short8 ov;
#pragma unroll
    for (int e = 0; e < 8; ++e) ov[e] = f2bf(accv[e] * inv);
    *(short8*)(Ob + (size_t)(b * S + i) * D + lane * 8) = ov;
}

// ---------------------------------------------------------------------------
// concat(emb, coarse) + LayerNorm -> seq (f32) + seq_bf (bf16)
// ---------------------------------------------------------------------------
__launch_bounds__(256)
__global__ void concat_ln_kernel(const float* __restrict__ emb, const float* __restrict__ coarse,
                                 const float* __restrict__ g, const float* __restrict__ bta,
                                 float* __restrict__ seq, short* __restrict__ seq_bf) {
    int row = blockIdx.x;
    int b = row / S, s = row % S;
    const float* src = (s < L) ? emb + ((size_t)b * L + s) * D
                               : coarse + ((size_t)b * LC + (s - L)) * D;
    __shared__ float red[256];
    int tid = threadIdx.x;
    float x0 = src[tid], x1 = src[tid + 256];
    red[tid] = x0 + x1;
    __syncthreads();
    for (int t = 128; t > 0; t >>= 1) { if (tid < t) red[tid] += red[tid + t]; __syncthreads(); }
    float mu = red[0] * (1.0f / D);
    __syncthreads();
    float d0 = x0 - mu, d1 = x1 - mu;
    red[tid] = d0 * d0 + d1 * d1;
    __syncthreads();
    for (int t = 128; t > 0; t >>= 1) { if (tid < t) red[tid] += red[tid + t]; __syncthreads(); }
    float rstd = rsqrtf(red[0] * (1.0f / D) + 1e-5f);
    float v0 = d0 * rstd * g[tid]       + bta[tid];
    float v1 = d1 * rstd * g[tid + 256] + bta[tid + 256];
    float* dst = seq + (size_t)row * D;
    dst[tid] = v0; dst[tid + 256] = v1;
    short* dbf = seq_bf + (size_t)row * D;
    dbf[tid] = f2bf(v0); dbf[tid + 256] = f2bf(v1);
}

// ---------------------------------------------------------------------------
// seq = LN(seq + add) in place; add is bf16; writes bf16 shadow
// ---------------------------------------------------------------------------
__launch_bounds__(256)
__global__ void add_ln_kernel(float* __restrict__ seq, const short* __restrict__ add,
                              const float* __restrict__ g, const float* __restrict__ bta,
                              short* __restrict__ seq_bf) {
    int row = blockIdx.x;
    __shared__ float red[256];
    int tid = threadIdx.x;
    float* srow = seq + (size_t)row * D;
    const short* arow = add + (size_t)row * D;
    float x0 = srow[tid] + bf2f(arow[tid]);
    float x1 = srow[tid + 256] + bf2f(arow[tid + 256]);
    red[tid] = x0 + x1;
    __syncthreads();
    for (int t = 128; t > 0; t >>= 1) { if (tid < t) red[tid] += red[tid + t]; __syncthreads(); }
    float mu = red[0] * (1.0f / D);
    __syncthreads();
    float d0 = x0 - mu, d1 = x1 - mu;
    red[tid] = d0 * d0 + d1 * d1;
    __syncthreads();
    for (int t = 128; t > 0; t >>= 1) { if (tid < t) red[tid] += red[tid + t]; __syncthreads(); }
    float rstd = rsqrtf(red[0] * (1.0f / D) + 1e-5f);
    float v0 = d0 * rstd * g[tid]       + bta[tid];
    float v1 = d1 * rstd * g[tid + 256] + bta[tid + 256];
    srow[tid] = v0; srow[tid + 256] = v1;
    short* dbf = seq_bf + (size_t)row * D;
    dbf[tid] = f2bf(v0); dbf[tid + 256] = f2bf(v1);
}

// ---------------------------------------------------------------------------
// prediction head, split-K with fused gather (es padded to 257 for banks)
// ---------------------------------------------------------------------------
__launch_bounds__(256)
__global__ void pred_kernel(const float* __restrict__ seq, const float* __restrict__ w,
                            float* __restrict__ part) {
    __shared__ float es[32][257];
    __shared__ float wsm[256][8];
    int tid = threadIdx.x;
    int n0 = blockIdx.x * 8;
    int ks = blockIdx.y;              // K slice: rows ks*256 .. ks*256+255
    int k0 = ks * 256;
    const int pos[4] = {335, 419, 440, 445};
    int seg = ks >> 1;
    int dbase = (ks & 1) * 256;
#pragma unroll 8
    for (int r = 0; r < 32; ++r)
        es[r][tid] = seq[((size_t)r * S + pos[seg]) * D + dbase + tid];
#pragma unroll
    for (int e = 0; e < 8; ++e)
        wsm[tid][e] = w[(size_t)(k0 + tid) * PRED_N + n0 + e];
    __syncthreads();
    int b = tid >> 3, nn = tid & 7;
    float acc = 0.0f;
#pragma unroll 8
    for (int kk = 0; kk < 256; ++kk)
        acc += es[b][kk] * wsm[kk][nn];
    part[(size_t)ks * (BB * PRED_N) + (size_t)b * PRED_N + n0 + nn] = acc;
}

__launch_bounds__(256)
__global__ void pred_reduce_kernel(const float* __restrict__ part, float* __restrict__ out) {
    int idx = blockIdx.x * 256 + threadIdx.x;
    if (idx >= BB * PRED_N) return;
    float s = 0.0f;
#pragma unroll
    for (int k = 0; k < 8; ++k) s += part[(size_t)k * (BB * PRED_N) + idx];
    out[idx] = s;
}

// ---------------------------------------------------------------------------
extern "C" void kernel_launch(void* const* d_in, const int* in_sizes, int n_in,
                              void* d_out, int out_size, void* d_ws, size_t ws_size,
                              hipStream_t stream) {
    const float* x_enc      = (const float*)d_in[0];
    const float* x_mark_enc = (const float*)d_in[1];
    const float* conv_embed_w = (const float*)d_in[4];
    const float* time_w  = (const float*)d_in[5];
    const float* time_b  = (const float*)d_in[6];
    const float* down_w  = (const float*)d_in[7];
    const float* down_b  = (const float*)d_in[8];
    const float* cscm_w  = (const float*)d_in[9];
    const float* cscm_b  = (const float*)d_in[10];
    const float* bn_g    = (const float*)d_in[11];
    const float* bn_b    = (const float*)d_in[12];
    const float* up_w    = (const float*)d_in[13];
    const float* up_b    = (const float*)d_in[14];
    const float* cln_g   = (const float*)d_in[15];
    const float* cln_b   = (const float*)d_in[16];
    const float* wq      = (const float*)d_in[17];
    const float* wk      = (const float*)d_in[18];
    const float* wv      = (const float*)d_in[19];
    const float* wo      = (const float*)d_in[20];
    const float* ln1_g   = (const float*)d_in[21];
    const float* ln1_b   = (const float*)d_in[22];
    const float* ffn_w1  = (const float*)d_in[23];
    const float* ffn_b1  = (const float*)d_in[24];
    const float* ffn_w2  = (const float*)d_in[25];
    const float* ffn_b2  = (const float*)d_in[26];
    const float* ln2_g   = (const float*)d_in[27];
    const float* ln2_b   = (const float*)d_in[28];
    const float* pred_w  = (const float*)d_in[29];
    float* out = (float*)d_out;

    // ---- workspace layout (bytes, 256-aligned) ----
    char* w8 = (char*)d_ws;
    size_t off = 0;
    auto alloc = [&](size_t bytes) {
        void* p = w8 + off;
        off = (off + bytes + 255) & ~(size_t)255;
        return p;
    };
    float* emb    = (float*)alloc((size_t)BB * L * D * 4);
    short* emb_bf = (short*)alloc((size_t)BB * L * D * 2);
    short* xd_bf  = (short*)alloc((size_t)BB * L * DBOT * 2);          // [2688][512] view
    short* cs1_bf = (short*)alloc((size_t)MCONV2P * 512 * 2);          // conv1 out (+pad view)
    short* cs2_bf = (short*)alloc((size_t)MCONV2P * DBOT * 2);         // conv2 out (+pad rows)
    short* cs3_bf = (short*)alloc((size_t)BB * L3 * DBOT * 2);
    short* csc_bf = (short*)alloc((size_t)MCAT * DBOT * 2);
    float* coarse = (float*)alloc((size_t)MCAT * D * 4);
    float* seq    = (float*)alloc((size_t)BB * S * D * 4);
    short* T1     = (short*)alloc((size_t)MP * D * 2);
    float* part   = (float*)alloc((size_t)8 * BB * PRED_N * 4);
    short* seq_bf = (short*)alloc((size_t)MP * D * 2);
    short* QKV    = (short*)alloc((size_t)MP * 3 * D * 2);  // + Ob contiguous =
    short* Ob     = (short*)alloc((size_t)MP * D * 2);      // hidden [MP][2048]
    short* hidden = QKV;
    short* wqkvT  = (short*)alloc((size_t)NLAYER * 3 * D * D * 2);
    short* woT    = (short*)alloc((size_t)NLAYER * D * D * 2);
    short* w1T    = (short*)alloc((size_t)NLAYER * DFF * D * 2);
    short* w2T    = (short*)alloc((size_t)NLAYER * D * DFF * 2);
    short* downT  = (short*)alloc((size_t)DBOT * D * 2);
    short* upT    = (short*)alloc((size_t)D * DBOT * 2);
    short* cscmT  = (short*)alloc((size_t)2 * DBOT * 512 * 2);
    float* csc_sc = (float*)alloc((size_t)3 * DBOT * 4);
    float* csc_sh = (float*)alloc((size_t)3 * DBOT * 4);
    int*   nbr    = (int*)alloc((size_t)S * NMAX * 4);
    (void)ws_size; (void)in_sizes; (void)n_in; (void)out_size;

    const int rowsL = BB * L;   // 10752 = 84*128
    const int rowsS = BB * S;   // 14272
    dim3 blk(256);

    // 0. weight convert+transpose
    wtrans_qkvo<<<dim3(16, 16, 4 * NLAYER), blk, 0, stream>>>(wq, wk, wv, wo, wqkvT, woT);
    wtrans_ffn<<<dim3(64, 16, 2 * NLAYER), blk, 0, stream>>>(ffn_w1, ffn_w2, w1T, w2T);
    wtrans_one<<<dim3(DBOT / 32, D / 32), blk, 0, stream>>>(down_w, downT, D, DBOT);
    wtrans_one<<<dim3(D / 32, DBOT / 32), blk, 0, stream>>>(up_w, upT, DBOT, D);
    cscm_prep<<<dim3((2 * DBOT * 512 + 255) / 256), blk, 0, stream>>>(
        cscm_w, cscm_b, bn_g, bn_b, cscmT, csc_sc, csc_sh);
    // 1. embedding + neighbor lists
    embed_kernel<<<dim3(((size_t)BB * L * D + 255) / 256), blk, 0, stream>>>(
        x_enc, x_mark_enc, conv_embed_w, time_w, time_b, emb, emb_bf);
    nbr_kernel<<<dim3((S + 63) / 64), dim3(64), 0, stream>>>(nbr);
    // 2. down projection -> bf16 (M=10752, N=128, K=512)
    mfma_gemm<4><<<dim3(1, rowsL / 128), blk, 0, stream>>>(
        emb_bf, downT, down_b, nullptr, xd_bf, D, DBOT);
    // 3. CSCM pyramid: conv1/conv2 as GEMM (im2col = reshape since k=stride=4)
    mfma_gemm<5><<<dim3(1, MCONV1 / 128), blk, 0, stream>>>(
        xd_bf, cscmT, csc_sc, csc_sh, cs1_bf, 512, DBOT);
    mfma_gemm<5><<<dim3(1, MCONV2P / 128), blk, 0, stream>>>(
        cs1_bf, cscmT + (size_t)DBOT * 512, csc_sc + DBOT, csc_sh + DBOT,
        cs2_bf, 512, DBOT);
    cscm_conv_bf16<<<dim3(BB * L3), dim3(DBOT), 0, stream>>>(
        cs2_bf, L2, cs3_bf, cscm_w + 2 * DBOT * DBOT * 4,
        cscm_b + 2 * DBOT, bn_g + 2 * DBOT, bn_b + 2 * DBOT, L3);
    // 4. up projection: concat (bf16) -> MFMA (M=3584, N=512, K=128)
    concat_cs_kernel<<<dim3((MCAT * DBOT + 255) / 256), blk, 0, stream>>>(
        cs1_bf, cs2_bf, cs3_bf, csc_bf);
    mfma_gemm<1><<<dim3(D / 128, MCAT / 128), blk, 0, stream>>>(
        csc_bf, upT, up_b, nullptr, coarse, DBOT, D);
    // 5. concat + LN
    concat_ln_kernel<<<dim3(rowsS), blk, 0, stream>>>(emb, coarse, cln_g, cln_b, seq, seq_bf);

    // 6. encoder layers
    const int gy  = MP / 128;  // 112
    const int gy2 = MP / 256;  // 56
    for (int l = 0; l < NLAYER; ++l) {
        mfma_gemm256<2><<<dim3(3 * D / 256, gy2), dim3(512), 0, stream>>>(
            seq_bf, wqkvT + (size_t)l * 3 * D * D, nullptr, QKV, D, 3 * D);
        attn_sparse_kernel<<<dim3(rowsS / 4), blk, 0, stream>>>(QKV, nbr, Ob);
        mfma_gemm<2><<<dim3(D / 128, gy), blk, 0, stream>>>(
            Ob, woT + (size_t)l * D * D, nullptr, nullptr, T1, D, D);
        add_ln_kernel<<<dim3(rowsS), blk, 0, stream>>>(
            seq, T1, ln1_g + (size_t)l * D, ln1_b + (size_t)l * D, seq_bf);
        mfma_gemm256<3><<<dim3(DFF / 256, gy2), dim3(512), 0, stream>>>(
            seq_bf, w1T + (size_t)l * DFF * D, ffn_b1 + (size_t)l * DFF, hidden, D, DFF);
        mfma_gemm<4><<<dim3(D / 128, gy), blk, 0, stream>>>(
            hidden, w2T + (size_t)l * D * DFF, ffn_b2 + (size_t)l * D, nullptr, T1, DFF, D);
        add_ln_kernel<<<dim3(rowsS), blk, 0, stream>>>(
            seq, T1, ln2_g + (size_t)l * D, ln2_b + (size_t)l * D, seq_bf);
    }

    // 7. prediction head (split-K, gather fused) + reduce
    pred_kernel<<<dim3(PRED_N / 8, 8), blk, 0, stream>>>(seq, pred_w, part);
    pred_reduce_kernel<<<dim3((BB * PRED_N + 255) / 256), blk, 0, stream>>>(part, out);
}

// Round 11
// 861.748 us; speedup vs baseline: 1.3128x; 1.0014x over previous
//
#include <hip/hip_runtime.h>
#include <math.h>

// ---- problem constants ----
constexpr int BB   = 32;    // batch
constexpr int L    = 336;   // seq_len
constexpr int CIN  = 7;
constexpr int MARK = 4;
constexpr int D    = 512;   // d_model
constexpr int DFF  = 2048;
constexpr int NH   = 8;
constexpr int HD   = 64;    // dk = dv
constexpr int S    = 446;   // 336+84+21+5
constexpr int DBOT = 128;
constexpr int L1 = 84, L2 = 21, L3 = 5;
constexpr int LC = 110;     // 84+21+5
constexpr int NLAYER = 3;
constexpr int PRED_N = 672; // 96*7
constexpr int MP   = 14336; // BB*S=14272 padded to multiple of 256
constexpr int NMAX = 12;    // max sparse neighbors (real max 10)
constexpr int MCONV1 = BB * L1;          // 2688 = 21*128 (exact)
constexpr int MCONV2P = 768;             // BB*L2=672 padded to 6*128
constexpr int MCAT  = 3584;              // BB*LC=3520 padded to 28*128

using short8  = __attribute__((ext_vector_type(8))) short;
using float4v = __attribute__((ext_vector_type(4))) float;

__device__ inline short f2bf(float f) {
    union { float f; unsigned u; } v; v.f = f;
    unsigned r = v.u + 0x7fffu + ((v.u >> 16) & 1u);
    return (short)(r >> 16);
}
__device__ inline float bf2f(short h) {
    union { unsigned u; float f; } v; v.u = ((unsigned)(unsigned short)h) << 16;
    return v.f;
}

// async global->LDS, 16B per lane, wave-uniform LDS base + lane*16
__device__ inline void gload_lds16(const void* g, void* l) {
    __builtin_amdgcn_global_load_lds(
        (const __attribute__((address_space(1))) void*)g,
        (__attribute__((address_space(3))) void*)l, 16, 0, 0);
}

// Staging map (both GEMM kernels), conflict-free + coalesced:
// LDS 16B-chunk u encodes row = ((u>>3)<<1)|((u>>2)&1)  (row-PAIR interleave:
// even row's 64B then odd row's 64B share each 128B line), and k-slot
// s = u&3 holding global k-segment kg = s ^ ((u>>3)&3). Each 4-lane cluster
// still fetches one complete (permuted) 64B k-line -> fully coalesced.
// Reader (lane lr,lk; fragment row r_): rh=r_>>1, s = lk ^ (rh&3),
// chunk = rh*8 + (r_&1)*4 + s. Staged kg == s ^ (rh&3) == lk  (correct data),
// and each 8-lane phase covers all 32 banks exactly once: (r_&1) selects the
// 16-bank half, (rh&3)^lk walks the 4 quads -> 0 bank conflicts.

// ---------------------------------------------------------------------------
// 128x128 bf16 MFMA GEMM, BK=32, double-buffered, counted vmcnt(4) pipeline.
// EPI: 0 f32; 1 f32+bias; 2 bf16; 3 bf16+bias+gelu; 4 bf16+bias;
//      5 bf16, v = acc*bias[gn] + bias2[gn] then ELU  (fused conv BN+ELU)
// grid.y*128 rows / grid.x*128 cols must be readable/writable (M padded).
// ---------------------------------------------------------------------------
template<int EPI>
__launch_bounds__(256, 4)
__global__ void mfma_gemm(const short* __restrict__ A, const short* __restrict__ Bt,
                          const float* __restrict__ bias, const float* __restrict__ bias2,
                          void* __restrict__ Cout, int Kd, int Nd) {
    __shared__ short As[2][128 * 32];
    __shared__ short Bs[2][128 * 32];
    int tid = threadIdx.x;
    int nwg  = gridDim.x * gridDim.y;
    int orig = blockIdx.y * gridDim.x + blockIdx.x;
    int qq = nwg >> 3, rr = nwg & 7;
    int xcd = orig & 7, idx = orig >> 3;
    int wgid = (xcd < rr ? xcd * (qq + 1) : rr * (qq + 1) + (xcd - rr) * qq) + idx;
    int m0 = (wgid / gridDim.x) * 128, n0 = (wgid % gridDim.x) * 128;

    int lane = tid & 63, wid = tid >> 6;
    int wm = wid >> 1, wn = wid & 1;
    int lr = lane & 15, lk = lane >> 4;

    auto stage = [&](int buf, int k0) {
#pragma unroll
        for (int r = 0; r < 2; ++r) {
            int u = r * 256 + tid;                       // 512 chunks x 16B
            int row = ((u >> 3) << 1) | ((u >> 2) & 1);
            int kg  = (u & 3) ^ ((u >> 3) & 3);
            short* la = As[buf] + (size_t)(r * 256 + wid * 64) * 8;
            short* lb = Bs[buf] + (size_t)(r * 256 + wid * 64) * 8;
            gload_lds16(A + (size_t)(m0 + row) * Kd + k0 + kg * 8, la);
            gload_lds16(Bt + (size_t)(n0 + row) * Kd + k0 + kg * 8, lb);
        }
    };
    auto rd_off = [&](int row_) {
        int rh = row_ >> 1;
        int s  = lk ^ (rh & 3);
        return (size_t)(rh * 8 + (row_ & 1) * 4 + s) * 8;
    };

    float4v acc[4][4];
#pragma unroll
    for (int i = 0; i < 4; ++i)
#pragma unroll
        for (int j = 0; j < 4; ++j) acc[i][j] = 0;

    const int nt = Kd >> 5;
    stage(0, 0);
    for (int t = 0; t < nt; ++t) {
        int cur = t & 1;
        if (t + 1 < nt) {
            stage(cur ^ 1, (t + 1) * 32);
            asm volatile("s_waitcnt vmcnt(4)" ::: "memory");
        } else {
            asm volatile("s_waitcnt vmcnt(0)" ::: "memory");
        }
        __builtin_amdgcn_s_barrier();
        short8 af[4], bfv[4];
#pragma unroll
        for (int mi = 0; mi < 4; ++mi)
            af[mi] = *(const short8*)(As[cur] + rd_off(wm * 64 + mi * 16 + lr));
#pragma unroll
        for (int ni = 0; ni < 4; ++ni)
            bfv[ni] = *(const short8*)(Bs[cur] + rd_off(wn * 64 + ni * 16 + lr));
        __builtin_amdgcn_s_setprio(1);
#pragma unroll
        for (int mi = 0; mi < 4; ++mi)
#pragma unroll
            for (int ni = 0; ni < 4; ++ni)
                acc[mi][ni] = __builtin_amdgcn_mfma_f32_16x16x32_bf16(
                    af[mi], bfv[ni], acc[mi][ni], 0, 0, 0);
        __builtin_amdgcn_s_setprio(0);
        __builtin_amdgcn_s_barrier();
    }

#pragma unroll
    for (int mi = 0; mi < 4; ++mi) {
        int gm = m0 + wm * 64 + mi * 16 + lk * 4;
#pragma unroll
        for (int ni = 0; ni < 4; ++ni) {
            int gn = n0 + wn * 64 + ni * 16 + lr;
            float bsv = (EPI == 1 || EPI == 3 || EPI == 4) ? bias[gn] : 0.0f;
            float sc = (EPI == 5) ? bias[gn]  : 0.0f;
            float sh = (EPI == 5) ? bias2[gn] : 0.0f;
#pragma unroll
            for (int e = 0; e < 4; ++e) {
                float v = acc[mi][ni][e] + bsv;
                if (EPI == 3) v = 0.5f * v * (1.0f + erff(v * 0.70710678118654752f));
                if (EPI == 5) { v = v * sc + sh; v = v > 0.0f ? v : (expf(v) - 1.0f); }
                if (EPI <= 1) ((float*)Cout)[(size_t)(gm + e) * Nd + gn] = v;
                else          ((short*)Cout)[(size_t)(gm + e) * Nd + gn] = f2bf(v);
            }
        }
    }
}

// ---------------------------------------------------------------------------
// 256x256 bf16 MFMA GEMM (wide-N shapes: FFN1, QKV). 8 waves (2M x 4N),
// BK=32 double-buffered (64KB LDS), same counted-vmcnt skeleton & staging.
// ---------------------------------------------------------------------------
template<int EPI>
__launch_bounds__(512, 2)
__global__ void mfma_gemm256(const short* __restrict__ A, const short* __restrict__ Bt,
                             const float* __restrict__ bias, void* __restrict__ Cout,
                             int Kd, int Nd) {
    __shared__ short As[2][256 * 32];
    __shared__ short Bs[2][256 * 32];
    int tid = threadIdx.x;
    int nwg  = gridDim.x * gridDim.y;
    int orig = blockIdx.y * gridDim.x + blockIdx.x;
    int qq = nwg >> 3, rr = nwg & 7;
    int xcd = orig & 7, idx = orig >> 3;
    int wgid = (xcd < rr ? xcd * (qq + 1) : rr * (qq + 1) + (xcd - rr) * qq) + idx;
    int m0 = (wgid / gridDim.x) * 256, n0 = (wgid % gridDim.x) * 256;

    int lane = tid & 63, wid = tid >> 6;
    int wm = wid >> 2, wn = wid & 3;
    int lr = lane & 15, lk = lane >> 4;

    auto stage = [&](int buf, int k0) {
#pragma unroll
        for (int r = 0; r < 2; ++r) {
            int u = r * 512 + tid;                       // 1024 chunks x 16B
            int row = ((u >> 3) << 1) | ((u >> 2) & 1);
            int kg  = (u & 3) ^ ((u >> 3) & 3);
            short* la = As[buf] + (size_t)(r * 512 + wid * 64) * 8;
            short* lb = Bs[buf] + (size_t)(r * 512 + wid * 64) * 8;
            gload_lds16(A + (size_t)(m0 + row) * Kd + k0 + kg * 8, la);
            gload_lds16(Bt + (size_t)(n0 + row) * Kd + k0 + kg * 8, lb);
        }
    };
    auto rd_off = [&](int row_) {
        int rh = row_ >> 1;
        int s  = lk ^ (rh & 3);
        return (size_t)(rh * 8 + (row_ & 1) * 4 + s) * 8;
    };

    float4v acc[8][4];
#pragma unroll
    for (int i = 0; i < 8; ++i)
#pragma unroll
        for (int j = 0; j < 4; ++j) acc[i][j] = 0;

    const int nt = Kd >> 5;
    stage(0, 0);
    for (int t = 0; t < nt; ++t) {
        int cur = t & 1;
        if (t + 1 < nt) {
            stage(cur ^ 1, (t + 1) * 32);
            asm volatile("s_waitcnt vmcnt(4)" ::: "memory");
        } else {
            asm volatile("s_waitcnt vmcnt(0)" ::: "memory");
        }
        __builtin_amdgcn_s_barrier();
        short8 af[8], bfv[4];
#pragma unroll
        for (int mi = 0; mi < 8; ++mi)
            af[mi] = *(const short8*)(As[cur] + rd_off(wm * 128 + mi * 16 + lr));
#pragma unroll
        for (int ni = 0; ni < 4; ++ni)
            bfv[ni] = *(const short8*)(Bs[cur] + rd_off(wn * 64 + ni * 16 + lr));
        __builtin_amdgcn_s_setprio(1);
#pragma unroll
        for (int mi = 0; mi < 8; ++mi)
#pragma unroll
            for (int ni = 0; ni < 4; ++ni)
                acc[mi][ni] = __builtin_amdgcn_mfma_f32_16x16x32_bf16(
                    af[mi], bfv[ni], acc[mi][ni], 0, 0, 0);
        __builtin_amdgcn_s_setprio(0);
        __builtin_amdgcn_s_barrier();
    }

#pragma unroll
    for (int mi = 0; mi < 8; ++mi) {
        int gm = m0 + wm * 128 + mi * 16 + lk * 4;
#pragma unroll
        for (int ni = 0; ni < 4; ++ni) {
            int gn = n0 + wn * 64 + ni * 16 + lr;
            float bsv = (EPI == 1 || EPI == 3 || EPI == 4) ? bias[gn] : 0.0f;
#pragma unroll
            for (int e = 0; e < 4; ++e) {
                float v = acc[mi][ni][e] + bsv;
                if (EPI == 3) v = 0.5f * v * (1.0f + erff(v * 0.70710678118654752f));
                if (EPI <= 1) ((float*)Cout)[(size_t)(gm + e) * Nd + gn] = v;
                else          ((short*)Cout)[(size_t)(gm + e) * Nd + gn] = f2bf(v);
            }
        }
    }
}

// ---------------------------------------------------------------------------
// batched weight transpose+convert, 32x32 tiles, f32 W[Kd][Nd] -> bf16 Wt[Nd][Kd]
// ---------------------------------------------------------------------------
__device__ inline void wtrans_tile(const float* __restrict__ W, short* __restrict__ Wt,
                                   int Kd, int Nd, int n0, int k0, int tid) {
    __shared__ float tile[32][33];
    int tx = tid & 31, ty = tid >> 5; // ty 0..7
#pragma unroll
    for (int r = 0; r < 32; r += 8)
        tile[ty + r][tx] = W[(size_t)(k0 + ty + r) * Nd + n0 + tx];
    __syncthreads();
#pragma unroll
    for (int r = 0; r < 32; r += 8)
        Wt[(size_t)(n0 + ty + r) * Kd + k0 + tx] = f2bf(tile[tx][ty + r]);
}

// z = layer*4 + {0:q,1:k,2:v,3:o}; q/k/v pack into wqkvT [1536][512] per layer
__launch_bounds__(256)
__global__ void wtrans_qkvo(const float* __restrict__ wq, const float* __restrict__ wk,
                            const float* __restrict__ wv, const float* __restrict__ wo,
                            short* __restrict__ wqkvT, short* __restrict__ woT) {
    int z = blockIdx.z, l = z >> 2, part = z & 3;
    const float* src = (part == 0 ? wq : part == 1 ? wk : part == 2 ? wv : wo)
                       + (size_t)l * D * D;
    short* dst = (part < 3) ? wqkvT + (size_t)l * 3 * D * D + (size_t)part * D * D
                            : woT + (size_t)l * D * D;
    wtrans_tile(src, dst, D, D, blockIdx.x * 32, blockIdx.y * 32, threadIdx.x);
}

// z = layer*2 + {0:w1,1:w2}
__launch_bounds__(256)
__global__ void wtrans_ffn(const float* __restrict__ w1, const float* __restrict__ w2,
                           short* __restrict__ w1T, short* __restrict__ w2T) {
    int z = blockIdx.z, l = z >> 1, part = z & 1;
    int nt = part ? blockIdx.y : blockIdx.x;   // n-tiles: w1 64, w2 16
    int kt = part ? blockIdx.x : blockIdx.y;   // k-tiles: w1 16, w2 64
    if (part == 0)
        wtrans_tile(w1 + (size_t)l * D * DFF, w1T + (size_t)l * DFF * D,
                    D, DFF, nt * 32, kt * 32, threadIdx.x);
    else
        wtrans_tile(w2 + (size_t)l * DFF * D, w2T + (size_t)l * D * DFF,
                    DFF, D, nt * 32, kt * 32, threadIdx.x);
}

__launch_bounds__(256)
__global__ void wtrans_one(const float* __restrict__ W, short* __restrict__ Wt,
                           int Kd, int Nd) {
    wtrans_tile(W, Wt, Kd, Nd, blockIdx.x * 32, blockIdx.y * 32, threadIdx.x);
}

// ---------------------------------------------------------------------------
// CSCM prep: levels 0,1 weights -> GEMM layout cscmT[l][oc][r*128+c] (bf16);
// per-channel fused BN: sc = bn_g, sh = cb*bn_g + bn_b (all 3 levels)
// ---------------------------------------------------------------------------
__launch_bounds__(256)
__global__ void cscm_prep(const float* __restrict__ cw, const float* __restrict__ cb,
                          const float* __restrict__ bg, const float* __restrict__ bb,
                          short* __restrict__ cscmT, float* __restrict__ sc,
                          float* __restrict__ sh) {
    int idx = blockIdx.x * 256 + threadIdx.x;
    if (idx < 2 * DBOT * 512) {
        int l = idx >> 16;           // 128*512 = 65536
        int rem = idx & 65535;
        int oc = rem >> 9, j = rem & 511;
        int r = j >> 7, c = j & 127;
        cscmT[idx] = f2bf(cw[(((size_t)l * DBOT + oc) * DBOT + c) * 4 + r]);
    }
    if (idx < 3 * DBOT) {
        sc[idx] = bg[idx];
        sh[idx] = cb[idx] * bg[idx] + bb[idx];
    }
}

// ---------------------------------------------------------------------------
// Embedding: circular conv1d(k=3) + positional enc + mark @ time_w + time_b
// ---------------------------------------------------------------------------
__launch_bounds__(256)
__global__ void embed_kernel(const float* __restrict__ x_enc, const float* __restrict__ x_mark,
                             const float* __restrict__ cw, const float* __restrict__ tw,
                             const float* __restrict__ tb, float* __restrict__ emb,
                             short* __restrict__ emb_bf) {
    size_t idx = (size_t)blockIdx.x * 256 + threadIdx.x;
    if (idx >= (size_t)BB * L * D) return;
    int d = idx % D;
    int t = (idx / D) % L;
    int b = idx / ((size_t)D * L);
    float acc = tb[d];
#pragma unroll
    for (int w = 0; w < 3; ++w) {
        int s = t + w - 1;
        if (s < 0) s = L - 1;
        if (s >= L) s = 0;
        const float* xr = x_enc + ((size_t)b * L + s) * CIN;
        const float* wr = cw + (size_t)d * (CIN * 3) + w;
#pragma unroll
        for (int i = 0; i < CIN; ++i) acc += xr[i] * wr[i * 3];
    }
    int e = d & ~1;
    float div = expf(-(float)e * (logf(10000.0f) / (float)D));
    float arg = (float)t * div;
    acc += (d & 1) ? cosf(arg) : sinf(arg);
    const float* mr = x_mark + ((size_t)b * L + t) * MARK;
#pragma unroll
    for (int m = 0; m < MARK; ++m) acc += mr[m] * tw[m * D + d];
    emb[idx] = acc;
    emb_bf[idx] = f2bf(acc);
}

// ---------------------------------------------------------------------------
// CSCM conv level 3 only (tiny): bf16 in/out, f32 weights
// ---------------------------------------------------------------------------
__launch_bounds__(128)
__global__ void cscm_conv_bf16(const short* __restrict__ in, int inRowsPerB,
                               short* __restrict__ outp, const float* __restrict__ w,
                               const float* __restrict__ cb, const float* __restrict__ bng,
                               const float* __restrict__ bnb, int Lout) {
    int bid = blockIdx.x;
    int to = bid % Lout, b = bid / Lout;
    __shared__ float insh[4 * DBOT];
    int tid = threadIdx.x;
#pragma unroll
    for (int r = 0; r < 4; ++r)
        insh[r * DBOT + tid] = bf2f(in[((size_t)(b * inRowsPerB + to * 4 + r)) * DBOT + tid]);
    __syncthreads();
    float acc = cb[tid];
    const float* wr = w + (size_t)tid * (DBOT * 4);
    for (int c = 0; c < DBOT; ++c) {
#pragma unroll
        for (int r = 0; r < 4; ++r)
            acc += insh[r * DBOT + c] * wr[c * 4 + r];
    }
    acc = acc * bng[tid] + bnb[tid];
    outp[((size_t)(b * Lout + to)) * DBOT + tid] = f2bf(acc > 0.0f ? acc : (expf(acc) - 1.0f));
}

// ---------------------------------------------------------------------------
// concat pyramid outputs (bf16) -> csc [MCAT][128] for the up-projection GEMM
// ---------------------------------------------------------------------------
__launch_bounds__(256)
__global__ void concat_cs_kernel(const short* __restrict__ cs1, const short* __restrict__ cs2,
                                 const short* __restrict__ cs3, short* __restrict__ csc) {
    int idx = blockIdx.x * 256 + threadIdx.x;
    if (idx >= MCAT * DBOT) return;
    int m = idx >> 7, c = idx & 127;
    short v = 0;
    if (m < BB * LC) {
        int b = m / LC, t = m % LC;
        if (t < L1)           v = cs1[(size_t)(b * L1 + t) * DBOT + c];
        else if (t < L1 + L2) v = cs2[(size_t)(b * L2 + (t - L1)) * DBOT + c];
        else                  v = cs3[(size_t)(b * L3 + (t - L1 - L2)) * DBOT + c];
    }
    csc[idx] = v;
}

// ---------------------------------------------------------------------------
// sparse neighbor lists from the pyramid mask rules
// ---------------------------------------------------------------------------
__device__ inline void layer_of(int i, int& l, int& p) {
    if (i < 336)      { l = 0; p = i; }
    else if (i < 420) { l = 1; p = i - 336; }
    else if (i < 441) { l = 2; p = i - 420; }
    else              { l = 3; p = i - 441; }
}

__launch_bounds__(64)
__global__ void nbr_kernel(int* __restrict__ nbr) {
    int i = blockIdx.x * 64 + threadIdx.x;
    if (i >= S) return;
    const int sizes[4]  = {336, 84, 21, 5};
    const int starts[4] = {0, 336, 420, 441};
    int li, pi;
    layer_of(i, li, pi);
    int lst[NMAX];
    int cnt = 0;
    for (int d = -2; d <= 2; ++d) {
        int q = pi + d;
        if (q >= 0 && q < sizes[li]) lst[cnt++] = starts[li] + q;
    }
    if (li > 0) {
        int lo = pi * 4;
        int hi = (pi == sizes[li] - 1) ? sizes[li - 1] : (pi + 1) * 4;
        for (int c = lo; c < hi; ++c) lst[cnt++] = starts[li - 1] + c;
    }
    if (li < 3) {
        int q = pi >> 2;
        if (q > sizes[li + 1] - 1) q = sizes[li + 1] - 1;
        lst[cnt++] = starts[li + 1] + q;
    }
    for (int j = 0; j < NMAX; ++j) nbr[i * NMAX + j] = (j < cnt) ? lst[j] : -1;
}

// ---------------------------------------------------------------------------
// sparse attention: one wave per (b,i), all 8 heads.
// ---------------------------------------------------------------------------
__launch_bounds__(256)
__global__ void attn_sparse_kernel(const short* __restrict__ QKV, const int* __restrict__ nbr,
                                   short* __restrict__ Ob) {
    int wid  = blockIdx.x * 4 + (threadIdx.x >> 6);   // (b*S+i), exact: BB*S%4==0
    int lane = threadIdx.x & 63;
    int i = wid % S, b = wid / S;
    const short8 qv = *(const short8*)(QKV + (size_t)(b * S + i) * 1536 + lane * 8);
    float qf[8];
#pragma unroll
    for (int e = 0; e < 8; ++e) qf[e] = bf2f(qv[e]);
    int nb[NMAX];
    const int* nr = nbr + i * NMAX;
#pragma unroll
    for (int j = 0; j < NMAX; ++j) nb[j] = nr[j];
    float sc[NMAX];
#pragma unroll
    for (int j = 0; j < NMAX; ++j) {
        float s = -1e30f;
        if (nb[j] >= 0) {
            const short8 kv = *(const short8*)(QKV + (size_t)(b * S + nb[j]) * 1536 + 512 + lane * 8);
            s = 0.0f;
#pragma unroll
            for (int e = 0; e < 8; ++e) s += qf[e] * bf2f(kv[e]);
            s += __shfl_xor(s, 1); s += __shfl_xor(s, 2); s += __shfl_xor(s, 4);
            s *= 0.125f; // 1/sqrt(64)
        }
        sc[j] = s;
    }
    float mx = sc[0];
#pragma unroll
    for (int j = 1; j < NMAX; ++j) mx = fmaxf(mx, sc[j]);
    float sum = 0.0f;
    float accv[8] = {};
#pragma unroll
    for (int j = 0; j < NMAX; ++j) {
        float p = expf(sc[j] - mx);   // invalid -> exp(-huge) = 0
        sum += p;
        if (nb[j] >= 0) {
            const short8 vv = *(const short8*)(QKV + (size_t)(b * S + nb[j]) * 1536 + 1024 + lane * 8);
#pragma unroll
            for (int e = 0; e < 8; ++e) accv[e] += p * bf2f(vv[e]);
        }
    }
    float inv = 1.0f / sum;
    short8 ov;
#pragma unroll
    for (int e = 0; e < 8; ++e) ov[e] = f2bf(accv[e] * inv);
    *(short8*)(Ob + (size_t)(b * S + i) * D + lane * 8) = ov;
}

// ---------------------------------------------------------------------------
// concat(emb, coarse) + LayerNorm -> seq (f32) + seq_bf (bf16)
// ---------------------------------------------------------------------------
__launch_bounds__(256)
__global__ void concat_ln_kernel(const float* __restrict__ emb, const float* __restrict__ coarse,
                                 const float* __restrict__ g, const float* __restrict__ bta,
                                 float* __restrict__ seq, short* __restrict__ seq_bf) {
    int row = blockIdx.x;
    int b = row / S, s = row % S;
    const float* src = (s < L) ? emb + ((size_t)b * L + s) * D
                               : coarse + ((size_t)b * LC + (s - L)) * D;
    __shared__ float red[256];
    int tid = threadIdx.x;
    float x0 = src[tid], x1 = src[tid + 256];
    red[tid] = x0 + x1;
    __syncthreads();
    for (int t = 128; t > 0; t >>= 1) { if (tid < t) red[tid] += red[tid + t]; __syncthreads(); }
    float mu = red[0] * (1.0f / D);
    __syncthreads();
    float d0 = x0 - mu, d1 = x1 - mu;
    red[tid] = d0 * d0 + d1 * d1;
    __syncthreads();
    for (int t = 128; t > 0; t >>= 1) { if (tid < t) red[tid] += red[tid + t]; __syncthreads(); }
    float rstd = rsqrtf(red[0] * (1.0f / D) + 1e-5f);
    float v0 = d0 * rstd * g[tid]       + bta[tid];
    float v1 = d1 * rstd * g[tid + 256] + bta[tid + 256];
    float* dst = seq + (size_t)row * D;
    dst[tid] = v0; dst[tid + 256] = v1;
    short* dbf = seq_bf + (size_t)row * D;
    dbf[tid] = f2bf(v0); dbf[tid + 256] = f2bf(v1);
}

// ---------------------------------------------------------------------------
// seq = LN(seq + add) in place; add is bf16; writes bf16 shadow
// ---------------------------------------------------------------------------
__launch_bounds__(256)
__global__ void add_ln_kernel(float* __restrict__ seq, const short* __restrict__ add,
                              const float* __restrict__ g, const float* __restrict__ bta,
                              short* __restrict__ seq_bf) {
    int row = blockIdx.x;
    __shared__ float red[256];
    int tid = threadIdx.x;
    float* srow = seq + (size_t)row * D;
    const short* arow = add + (size_t)row * D;
    float x0 = srow[tid] + bf2f(arow[tid]);
    float x1 = srow[tid + 256] + bf2f(arow[tid + 256]);
    red[tid] = x0 + x1;
    __syncthreads();
    for (int t = 128; t > 0; t >>= 1) { if (tid < t) red[tid] += red[tid + t]; __syncthreads(); }
    float mu = red[0] * (1.0f / D);
    __syncthreads();
    float d0 = x0 - mu, d1 = x1 - mu;
    red[tid] = d0 * d0 + d1 * d1;
    __syncthreads();
    for (int t = 128; t > 0; t >>= 1) { if (tid < t) red[tid] += red[tid + t]; __syncthreads(); }
    float rstd = rsqrtf(red[0] * (1.0f / D) + 1e-5f);
    float v0 = d0 * rstd * g[tid]       + bta[tid];
    float v1 = d1 * rstd * g[tid + 256] + bta[tid + 256];
    srow[tid] = v0; srow[tid + 256] = v1;
    short* dbf = seq_bf + (size_t)row * D;
    dbf[tid] = f2bf(v0); dbf[tid + 256] = f2bf(v1);
}

// ---------------------------------------------------------------------------
// prediction head, split-K with fused gather (es padded to 257 for banks)
// ---------------------------------------------------------------------------
__launch_bounds__(256)
__global__ void pred_kernel(const float* __restrict__ seq, const float* __restrict__ w,
                            float* __restrict__ part) {
    __shared__ float es[32][257];
    __shared__ float wsm[256][8];
    int tid = threadIdx.x;
    int n0 = blockIdx.x * 8;
    int ks = blockIdx.y;              // K slice: rows ks*256 .. ks*256+255
    int k0 = ks * 256;
    const int pos[4] = {335, 419, 440, 445};
    int seg = ks >> 1;
    int dbase = (ks & 1) * 256;
#pragma unroll 8
    for (int r = 0; r < 32; ++r)
        es[r][tid] = seq[((size_t)r * S + pos[seg]) * D + dbase + tid];
#pragma unroll
    for (int e = 0; e < 8; ++e)
        wsm[tid][e] = w[(size_t)(k0 + tid) * PRED_N + n0 + e];
    __syncthreads();
    int b = tid >> 3, nn = tid & 7;
    float acc = 0.0f;
#pragma unroll 8
    for (int kk = 0; kk < 256; ++kk)
        acc += es[b][kk] * wsm[kk][nn];
    part[(size_t)ks * (BB * PRED_N) + (size_t)b * PRED_N + n0 + nn] = acc;
}

__launch_bounds__(256)
__global__ void pred_reduce_kernel(const float* __restrict__ part, float* __restrict__ out) {
    int idx = blockIdx.x * 256 + threadIdx.x;
    if (idx >= BB * PRED_N) return;
    float s = 0.0f;
#pragma unroll
    for (int k = 0; k < 8; ++k) s += part[(size_t)k * (BB * PRED_N) + idx];
    out[idx] = s;
}

// ---------------------------------------------------------------------------
extern "C" void kernel_launch(void* const* d_in, const int* in_sizes, int n_in,
                              void* d_out, int out_size, void* d_ws, size_t ws_size,
                              hipStream_t stream) {
    const float* x_enc      = (const float*)d_in[0];
    const float* x_mark_enc = (const float*)d_in[1];
    const float* conv_embed_w = (const float*)d_in[4];
    const float* time_w  = (const float*)d_in[5];
    const float* time_b  = (const float*)d_in[6];
    const float* down_w  = (const float*)d_in[7];
    const float* down_b  = (const float*)d_in[8];
    const float* cscm_w  = (const float*)d_in[9];
    const float* cscm_b  = (const float*)d_in[10];
    const float* bn_g    = (const float*)d_in[11];
    const float* bn_b    = (const float*)d_in[12];
    const float* up_w    = (const float*)d_in[13];
    const float* up_b    = (const float*)d_in[14];
    const float* cln_g   = (const float*)d_in[15];
    const float* cln_b   = (const float*)d_in[16];
    const float* wq      = (const float*)d_in[17];
    const float* wk      = (const float*)d_in[18];
    const float* wv      = (const float*)d_in[19];
    const float* wo      = (const float*)d_in[20];
    const float* ln1_g   = (const float*)d_in[21];
    const float* ln1_b   = (const float*)d_in[22];
    const float* ffn_w1  = (const float*)d_in[23];
    const float* ffn_b1  = (const float*)d_in[24];
    const float* ffn_w2  = (const float*)d_in[25];
    const float* ffn_b2  = (const float*)d_in[26];
    const float* ln2_g   = (const float*)d_in[27];
    const float* ln2_b   = (const float*)d_in[28];
    const float* pred_w  = (const float*)d_in[29];
    float* out = (float*)d_out;

    // ---- workspace layout (bytes, 256-aligned) ----
    char* w8 = (char*)d_ws;
    size_t off = 0;
    auto alloc = [&](size_t bytes) {
        void* p = w8 + off;
        off = (off + bytes + 255) & ~(size_t)255;
        return p;
    };
    float* emb    = (float*)alloc((size_t)BB * L * D * 4);
    short* emb_bf = (short*)alloc((size_t)BB * L * D * 2);
    short* xd_bf  = (short*)alloc((size_t)BB * L * DBOT * 2);          // [2688][512] view
    short* cs1_bf = (short*)alloc((size_t)MCONV2P * 512 * 2);          // conv1 out (+pad view)
    short* cs2_bf = (short*)alloc((size_t)MCONV2P * DBOT * 2);         // conv2 out (+pad rows)
    short* cs3_bf = (short*)alloc((size_t)BB * L3 * DBOT * 2);
    short* csc_bf = (short*)alloc((size_t)MCAT * DBOT * 2);
    float* coarse = (float*)alloc((size_t)MCAT * D * 4);
    float* seq    = (float*)alloc((size_t)BB * S * D * 4);
    short* T1     = (short*)alloc((size_t)MP * D * 2);
    float* part   = (float*)alloc((size_t)8 * BB * PRED_N * 4);
    short* seq_bf = (short*)alloc((size_t)MP * D * 2);
    short* QKV    = (short*)alloc((size_t)MP * 3 * D * 2);  // + Ob contiguous =
    short* Ob     = (short*)alloc((size_t)MP * D * 2);      // hidden [MP][2048]
    short* hidden = QKV;
    short* wqkvT  = (short*)alloc((size_t)NLAYER * 3 * D * D * 2);
    short* woT    = (short*)alloc((size_t)NLAYER * D * D * 2);
    short* w1T    = (short*)alloc((size_t)NLAYER * DFF * D * 2);
    short* w2T    = (short*)alloc((size_t)NLAYER * D * DFF * 2);
    short* downT  = (short*)alloc((size_t)DBOT * D * 2);
    short* upT    = (short*)alloc((size_t)D * DBOT * 2);
    short* cscmT  = (short*)alloc((size_t)2 * DBOT * 512 * 2);
    float* csc_sc = (float*)alloc((size_t)3 * DBOT * 4);
    float* csc_sh = (float*)alloc((size_t)3 * DBOT * 4);
    int*   nbr    = (int*)alloc((size_t)S * NMAX * 4);
    (void)ws_size; (void)in_sizes; (void)n_in; (void)out_size;

    const int rowsL = BB * L;   // 10752 = 84*128
    const int rowsS = BB * S;   // 14272
    dim3 blk(256);

    // 0. weight convert+transpose
    wtrans_qkvo<<<dim3(16, 16, 4 * NLAYER), blk, 0, stream>>>(wq, wk, wv, wo, wqkvT, woT);
    wtrans_ffn<<<dim3(64, 16, 2 * NLAYER), blk, 0, stream>>>(ffn_w1, ffn_w2, w1T, w2T);
    wtrans_one<<<dim3(DBOT / 32, D / 32), blk, 0, stream>>>(down_w, downT, D, DBOT);
    wtrans_one<<<dim3(D / 32, DBOT / 32), blk, 0, stream>>>(up_w, upT, DBOT, D);
    cscm_prep<<<dim3((2 * DBOT * 512 + 255) / 256), blk, 0, stream>>>(
        cscm_w, cscm_b, bn_g, bn_b, cscmT, csc_sc, csc_sh);
    // 1. embedding + neighbor lists
    embed_kernel<<<dim3(((size_t)BB * L * D + 255) / 256), blk, 0, stream>>>(
        x_enc, x_mark_enc, conv_embed_w, time_w, time_b, emb, emb_bf);
    nbr_kernel<<<dim3((S + 63) / 64), dim3(64), 0, stream>>>(nbr);
    // 2. down projection -> bf16 (M=10752, N=128, K=512)
    mfma_gemm<4><<<dim3(1, rowsL / 128), blk, 0, stream>>>(
        emb_bf, downT, down_b, nullptr, xd_bf, D, DBOT);
    // 3. CSCM pyramid: conv1/conv2 as GEMM (im2col = reshape since k=stride=4)
    mfma_gemm<5><<<dim3(1, MCONV1 / 128), blk, 0, stream>>>(
        xd_bf, cscmT, csc_sc, csc_sh, cs1_bf, 512, DBOT);
    mfma_gemm<5><<<dim3(1, MCONV2P / 128), blk, 0, stream>>>(
        cs1_bf, cscmT + (size_t)DBOT * 512, csc_sc + DBOT, csc_sh + DBOT,
        cs2_bf, 512, DBOT);
    cscm_conv_bf16<<<dim3(BB * L3), dim3(DBOT), 0, stream>>>(
        cs2_bf, L2, cs3_bf, cscm_w + 2 * DBOT * DBOT * 4,
        cscm_b + 2 * DBOT, bn_g + 2 * DBOT, bn_b + 2 * DBOT, L3);
    // 4. up projection: concat (bf16) -> MFMA (M=3584, N=512, K=128)
    concat_cs_kernel<<<dim3((MCAT * DBOT + 255) / 256), blk, 0, stream>>>(
        cs1_bf, cs2_bf, cs3_bf, csc_bf);
    mfma_gemm<1><<<dim3(D / 128, MCAT / 128), blk, 0, stream>>>(
        csc_bf, upT, up_b, nullptr, coarse, DBOT, D);
    // 5. concat + LN
    concat_ln_kernel<<<dim3(rowsS), blk, 0, stream>>>(emb, coarse, cln_g, cln_b, seq, seq_bf);

    // 6. encoder layers
    const int gy  = MP / 128;  // 112
    const int gy2 = MP / 256;  // 56
    for (int l = 0; l < NLAYER; ++l) {
        mfma_gemm256<2><<<dim3(3 * D / 256, gy2), dim3(512), 0, stream>>>(
            seq_bf, wqkvT + (size_t)l * 3 * D * D, nullptr, QKV, D, 3 * D);
        attn_sparse_kernel<<<dim3(rowsS / 4), blk, 0, stream>>>(QKV, nbr, Ob);
        mfma_gemm<2><<<dim3(D / 128, gy), blk, 0, stream>>>(
            Ob, woT + (size_t)l * D * D, nullptr, nullptr, T1, D, D);
        add_ln_kernel<<<dim3(rowsS), blk, 0, stream>>>(
            seq, T1, ln1_g + (size_t)l * D, ln1_b + (size_t)l * D, seq_bf);
        mfma_gemm256<3><<<dim3(DFF / 256, gy2), dim3(512), 0, stream>>>(
            seq_bf, w1T + (size_t)l * DFF * D, ffn_b1 + (size_t)l * DFF, hidden, D, DFF);
        mfma_gemm<4><<<dim3(D / 128, gy), blk, 0, stream>>>(
            hidden, w2T + (size_t)l * D * DFF, ffn_b2 + (size_t)l * D, nullptr, T1, DFF, D);
        add_ln_kernel<<<dim3(rowsS), blk, 0, stream>>>(
            seq, T1, ln2_g + (size_t)l * D, ln2_b + (size_t)l * D, seq_bf);
    }

    // 7. prediction head (split-K, gather fused) + reduce
    pred_kernel<<<dim3(PRED_N / 8, 8), blk, 0, stream>>>(seq, pred_w, part);
    pred_reduce_kernel<<<dim3((BB * PRED_N + 255) / 256), blk, 0, stream>>>(part, out);
}